// Round 1
// baseline (4629.659 us; speedup 1.0000x reference)
//
#include <hip/hip_runtime.h>
#include <hip/hip_bf16.h>

// ---------------------------------------------------------------------------
// GAT encoder, 2 layers. f32 throughout (correctness-first baseline).
// Layer: h = x@W; s=h@a_src; d=h@a_dst; e=leaky(s[src]+d[dst]);
//        m=segmax(e,dst); ex=exp(e-m[dst]); z=segsum(ex,dst);
//        out = segsum(ex*h[src],dst)/z + b   (alpha never materialized)
// ---------------------------------------------------------------------------

#define NEG_SLOPE 0.2f

// ---- float-as-ordered-uint encoding for atomicMax on floats ----
__device__ __forceinline__ unsigned enc_f32(float f) {
    unsigned u = __float_as_uint(f);
    return (u & 0x80000000u) ? ~u : (u | 0x80000000u);
}
__device__ __forceinline__ float dec_f32(unsigned u) {
    return (u & 0x80000000u) ? __uint_as_float(u ^ 0x80000000u)
                             : __uint_as_float(~u);
}

// ---- tiled f32 GEMM: C[M,Nn] = A[M,K] @ B[K,Nn] ----
// 64x64 tile, 16x16 threads, 4x4 microtile, BK=16.
__global__ __launch_bounds__(256) void gemm_f32(
    const float* __restrict__ A, const float* __restrict__ B,
    float* __restrict__ C, int M, int K, int Nn) {
    __shared__ float As[16][65];
    __shared__ float Bs[16][65];
    const int row0 = blockIdx.y * 64;
    const int col0 = blockIdx.x * 64;
    const int tid = threadIdx.x;
    const int tr = tid >> 4;   // 0..15
    const int tc = tid & 15;   // 0..15
    float acc[4][4] = {};
    for (int k0 = 0; k0 < K; k0 += 16) {
        #pragma unroll
        for (int l = 0; l < 4; ++l) {
            int idx = tid + l * 256;
            int mm = idx >> 4, kk = idx & 15;
            int r = row0 + mm;
            As[kk][mm] = (r < M) ? A[(size_t)r * K + k0 + kk] : 0.f;
        }
        #pragma unroll
        for (int l = 0; l < 4; ++l) {
            int idx = tid + l * 256;
            int kk = idx >> 6, cc = idx & 63;
            Bs[kk][cc] = B[(size_t)(k0 + kk) * Nn + col0 + cc];
        }
        __syncthreads();
        #pragma unroll
        for (int kk = 0; kk < 16; ++kk) {
            float a[4], b[4];
            #pragma unroll
            for (int i = 0; i < 4; ++i) a[i] = As[kk][tr * 4 + i];
            #pragma unroll
            for (int j = 0; j < 4; ++j) b[j] = Bs[kk][tc * 4 + j];
            #pragma unroll
            for (int i = 0; i < 4; ++i)
                #pragma unroll
                for (int j = 0; j < 4; ++j) acc[i][j] += a[i] * b[j];
        }
        __syncthreads();
    }
    #pragma unroll
    for (int i = 0; i < 4; ++i) {
        int r = row0 + tr * 4 + i;
        if (r < M) {
            #pragma unroll
            for (int j = 0; j < 4; ++j)
                C[(size_t)r * Nn + col0 + tc * 4 + j] = acc[i][j];
        }
    }
}

// ---- per-node dots: s[n] = h[n,:]·a_src, d[n] = h[n,:]·a_dst ----
template <int F>
__global__ __launch_bounds__(256) void rowdot_k(
    const float* __restrict__ h, const float* __restrict__ a_src,
    const float* __restrict__ a_dst, float* __restrict__ s,
    float* __restrict__ d, int N) {
    int w = (blockIdx.x * 256 + threadIdx.x) >> 6;  // wave index = node
    int lane = threadIdx.x & 63;
    if (w >= N) return;
    const float* hp = h + (size_t)w * F;
    float ss = 0.f, dd = 0.f;
    #pragma unroll
    for (int f = lane; f < F; f += 64) {
        float v = hp[f];
        ss += v * a_src[f];
        dd += v * a_dst[f];
    }
    #pragma unroll
    for (int off = 32; off; off >>= 1) {
        ss += __shfl_down(ss, off);
        dd += __shfl_down(dd, off);
    }
    if (lane == 0) { s[w] = ss; d[w] = dd; }
}

// ---- pass A: segment max over dst ----
__global__ __launch_bounds__(256) void edge_max_k(
    const int* __restrict__ srcE, const int* __restrict__ dstE,
    const float* __restrict__ s, const float* __restrict__ d,
    unsigned* __restrict__ m_u, int E, int N) {
    long long i = (long long)blockIdx.x * 256 + threadIdx.x;
    if (i >= (long long)E + N) return;
    int si, di;
    if (i < E) { si = srcE[i]; di = dstE[i]; }
    else       { si = di = (int)(i - E); }
    float e = s[si] + d[di];
    e = (e > 0.f) ? e : NEG_SLOPE * e;
    atomicMax(&m_u[di], enc_f32(e));
}

// ---- pass B: z[dst] += ex ; U[dst,:] += ex * h[src,:] ----
template <int F>
__global__ __launch_bounds__(256) void edge_accum_k(
    const int* __restrict__ srcE, const int* __restrict__ dstE,
    const float* __restrict__ s, const float* __restrict__ d,
    const unsigned* __restrict__ m_u, const float* __restrict__ h,
    float* __restrict__ z, float* __restrict__ U, int E, int N) {
    constexpr int TPE = F / 4;        // threads per edge (float4 each)
    constexpr int EPB = 256 / TPE;    // edges per block
    const int eib = threadIdx.x / TPE;
    const int lane = threadIdx.x % TPE;
    long long i = (long long)blockIdx.x * EPB + eib;
    if (i >= (long long)E + N) return;
    int si, di;
    if (i < E) { si = srcE[i]; di = dstE[i]; }
    else       { si = di = (int)(i - E); }
    float e = s[si] + d[di];
    e = (e > 0.f) ? e : NEG_SLOPE * e;
    float m = dec_f32(m_u[di]);
    float ex = __expf(e - m);
    if (lane == 0) atomicAdd(&z[di], ex);
    float4 v = *(const float4*)(h + (size_t)si * F + lane * 4);
    float* Up = U + (size_t)di * F + lane * 4;
    atomicAdd(Up + 0, ex * v.x);
    atomicAdd(Up + 1, ex * v.y);
    atomicAdd(Up + 2, ex * v.z);
    atomicAdd(Up + 3, ex * v.w);
}

// ---- pass C: out = U / z[n] + bias[f], optional relu ----
template <bool RELU, int F>
__global__ __launch_bounds__(256) void finalize_k(
    const float* __restrict__ U, const float* __restrict__ z,
    const float* __restrict__ bias, float* __restrict__ out, int N) {
    long long i = (long long)blockIdx.x * 256 + threadIdx.x;
    if (i >= (long long)N * F) return;
    int n = (int)(i >> (F == 256 ? 8 : 7));
    int f = (int)(i & (F - 1));
    float v = U[i] / z[n] + bias[f];
    if (RELU) v = fmaxf(v, 0.f);
    out[i] = v;
}

extern "C" void kernel_launch(void* const* d_in, const int* in_sizes, int n_in,
                              void* d_out, int out_size, void* d_ws, size_t ws_size,
                              hipStream_t stream) {
    const float* x      = (const float*)d_in[0];
    const int*   eidx   = (const int*)d_in[1];
    const float* W1     = (const float*)d_in[2];
    const float* a_src1 = (const float*)d_in[3];
    const float* a_dst1 = (const float*)d_in[4];
    const float* b1     = (const float*)d_in[5];
    const float* W2     = (const float*)d_in[6];
    const float* a_src2 = (const float*)d_in[7];
    const float* a_dst2 = (const float*)d_in[8];
    const float* b2     = (const float*)d_in[9];

    const int N = in_sizes[0] / 128;   // 50000
    const int E = in_sizes[1] / 2;     // 800000
    const int F_IN = 128, H = 256, F_OUT = 128;
    const long long EA = (long long)E + N;

    const int* srcE = eidx;        // edge_index[0]
    const int* dstE = eidx + E;    // edge_index[1]

    // workspace layout
    float*    h1   = (float*)d_ws;                 // N*256
    float*    Ubuf = h1 + (size_t)N * H;           // N*256 (U1; later h2 | U2)
    float*    sbuf = Ubuf + (size_t)N * H;         // N
    float*    dbuf = sbuf + N;                     // N
    unsigned* m_u  = (unsigned*)(dbuf + N);        // N
    float*    zbuf = (float*)(m_u + N);            // N

    float* out = (float*)d_out;

    // ---------------- layer 1 (F_IN=128 -> H=256, relu) ----------------
    {
        dim3 g1(H / 64, (N + 63) / 64);
        gemm_f32<<<g1, 256, 0, stream>>>(x, W1, h1, N, F_IN, H);

        int rb = (N * 64 + 255) / 256;
        rowdot_k<256><<<rb, 256, 0, stream>>>(h1, a_src1, a_dst1, sbuf, dbuf, N);

        hipMemsetAsync(m_u, 0, (size_t)N * 4, stream);
        hipMemsetAsync(zbuf, 0, (size_t)N * 4, stream);
        hipMemsetAsync(Ubuf, 0, (size_t)N * H * 4, stream);

        int mb = (int)((EA + 255) / 256);
        edge_max_k<<<mb, 256, 0, stream>>>(srcE, dstE, sbuf, dbuf, m_u, E, N);

        int ab = (int)((EA + 3) / 4);  // 4 edges/block at F=256
        edge_accum_k<256><<<ab, 256, 0, stream>>>(srcE, dstE, sbuf, dbuf, m_u,
                                                  h1, zbuf, Ubuf, E, N);

        int fb = (int)(((long long)N * H + 255) / 256);
        // write relu(U/z + b1) into h1 (h1 is dead now)
        finalize_k<true, 256><<<fb, 256, 0, stream>>>(Ubuf, zbuf, b1, h1, N);
    }

    // ---------------- layer 2 (H=256 -> F_OUT=128) ----------------
    {
        float* h2 = Ubuf;                       // N*128
        float* U2 = Ubuf + (size_t)N * F_OUT;   // N*128

        dim3 g2(F_OUT / 64, (N + 63) / 64);
        gemm_f32<<<g2, 256, 0, stream>>>(h1, W2, h2, N, H, F_OUT);

        int rb = (N * 64 + 255) / 256;
        rowdot_k<128><<<rb, 256, 0, stream>>>(h2, a_src2, a_dst2, sbuf, dbuf, N);

        hipMemsetAsync(m_u, 0, (size_t)N * 4, stream);
        hipMemsetAsync(zbuf, 0, (size_t)N * 4, stream);
        hipMemsetAsync(U2, 0, (size_t)N * F_OUT * 4, stream);

        int mb = (int)((EA + 255) / 256);
        edge_max_k<<<mb, 256, 0, stream>>>(srcE, dstE, sbuf, dbuf, m_u, E, N);

        int ab = (int)((EA + 7) / 8);  // 8 edges/block at F=128
        edge_accum_k<128><<<ab, 256, 0, stream>>>(srcE, dstE, sbuf, dbuf, m_u,
                                                  h2, zbuf, U2, E, N);

        int fb = (int)(((long long)N * F_OUT + 255) / 256);
        finalize_k<false, 128><<<fb, 256, 0, stream>>>(U2, zbuf, b2, out, N);
    }
}

// Round 3
// 577.818 us; speedup vs baseline: 8.0123x; 8.0123x over previous
//
#include <hip/hip_runtime.h>
#include <hip/hip_bf16.h>

// ---------------------------------------------------------------------------
// GAT encoder, 2 layers, f32. Round 3: CSR-gather aggregation, workspace
// shrunk to ~81MB (suspected ws overflow in round 2's ~107MB layout caused
// post-timing divergence). Layer-1 output g1 (N x 256) is split: cols 0..127
// live in d_out (scratch until the very end), cols 128..255 in ws.
// ---------------------------------------------------------------------------

#define NEG_SLOPE 0.2f

// ---- tiled f32 GEMM: C[M,Nn] = A[M,K] @ B[K,Nn] ----
// A is column-split: k<128 from A0, k>=128 from A1, both row-stride 128.
// 64x64 tile, 256 threads, 4x4 microtile, BK=16.
__global__ __launch_bounds__(256) void gemm_f32(
    const float* __restrict__ A0, const float* __restrict__ A1,
    const float* __restrict__ B, float* __restrict__ C,
    int M, int K, int Nn) {
    __shared__ float As[16][65];
    __shared__ float Bs[16][65];
    const int row0 = blockIdx.y * 64;
    const int col0 = blockIdx.x * 64;
    const int tid = threadIdx.x;
    const int tr = tid >> 4;
    const int tc = tid & 15;
    float acc[4][4] = {};
    for (int k0 = 0; k0 < K; k0 += 16) {
        const float* __restrict__ Ap = (k0 < 128) ? A0 : A1;
        const int kbase = k0 & 127;
        #pragma unroll
        for (int l = 0; l < 4; ++l) {
            int idx = tid + l * 256;
            int mm = idx >> 4, kk = idx & 15;
            int r = row0 + mm;
            As[kk][mm] = (r < M) ? Ap[(size_t)r * 128 + kbase + kk] : 0.f;
        }
        #pragma unroll
        for (int l = 0; l < 4; ++l) {
            int idx = tid + l * 256;
            int kk = idx >> 6, cc = idx & 63;
            Bs[kk][cc] = B[(size_t)(k0 + kk) * Nn + col0 + cc];
        }
        __syncthreads();
        #pragma unroll
        for (int kk = 0; kk < 16; ++kk) {
            float a[4], b[4];
            #pragma unroll
            for (int i = 0; i < 4; ++i) a[i] = As[kk][tr * 4 + i];
            #pragma unroll
            for (int j = 0; j < 4; ++j) b[j] = Bs[kk][tc * 4 + j];
            #pragma unroll
            for (int i = 0; i < 4; ++i)
                #pragma unroll
                for (int j = 0; j < 4; ++j) acc[i][j] += a[i] * b[j];
        }
        __syncthreads();
    }
    #pragma unroll
    for (int i = 0; i < 4; ++i) {
        int r = row0 + tr * 4 + i;
        if (r < M) {
            #pragma unroll
            for (int j = 0; j < 4; ++j)
                C[(size_t)r * Nn + col0 + tc * 4 + j] = acc[i][j];
        }
    }
}

// ---- per-node dots: s[n] = h[n,:]·a_src, d[n] = h[n,:]·a_dst ----
template <int F>
__global__ __launch_bounds__(256) void rowdot_k(
    const float* __restrict__ h, const float* __restrict__ a_src,
    const float* __restrict__ a_dst, float* __restrict__ s,
    float* __restrict__ d, int N) {
    int w = (blockIdx.x * 256 + threadIdx.x) >> 6;
    int lane = threadIdx.x & 63;
    if (w >= N) return;
    const float* hp = h + (size_t)w * F;
    float ss = 0.f, dd = 0.f;
    #pragma unroll
    for (int f = lane; f < F; f += 64) {
        float v = hp[f];
        ss += v * a_src[f];
        dd += v * a_dst[f];
    }
    #pragma unroll
    for (int off = 32; off; off >>= 1) {
        ss += __shfl_down(ss, off);
        dd += __shfl_down(dd, off);
    }
    if (lane == 0) { s[w] = ss; d[w] = dd; }
}

// ---- CSR build: histogram of dst (incl. self-loops) ----
__global__ __launch_bounds__(256) void hist_k(
    const int* __restrict__ dstE, int* __restrict__ cnt, int E, int N) {
    long long i = (long long)blockIdx.x * 256 + threadIdx.x;
    if (i >= (long long)E + N) return;
    int di = (i < E) ? dstE[i] : (int)(i - E);
    atomicAdd(&cnt[di], 1);
}

// ---- CSR build: one-block exclusive scan; rowptr[0..N]; cnt becomes cursor ----
__global__ __launch_bounds__(1024) void exscan_k(
    int* __restrict__ cnt, int* __restrict__ rowptr, int N) {
    __shared__ int sums[1024];
    const int t = threadIdx.x;
    const int chunk = (N + 1023) / 1024;
    const int begin = t * chunk;
    const int end = min(begin + chunk, N);
    int s = 0;
    for (int i = begin; i < end; ++i) s += cnt[i];
    sums[t] = s;
    __syncthreads();
    for (int off = 1; off < 1024; off <<= 1) {
        int v = (t >= off) ? sums[t - off] : 0;
        __syncthreads();
        sums[t] += v;
        __syncthreads();
    }
    int base = (t == 0) ? 0 : sums[t - 1];
    for (int i = begin; i < end; ++i) {
        int c = cnt[i];
        rowptr[i] = base;
        cnt[i] = base;   // cnt now serves as the scatter cursor
        base += c;
    }
    if (t == 1023) rowptr[N] = base;
}

// ---- CSR build: scatter src ids into dst-sorted order ----
__global__ __launch_bounds__(256) void scatter_k(
    const int* __restrict__ srcE, const int* __restrict__ dstE,
    int* __restrict__ cursor, int* __restrict__ ssrc, int E, int N) {
    long long i = (long long)blockIdx.x * 256 + threadIdx.x;
    if (i >= (long long)E + N) return;
    int si, di;
    if (i < E) { si = srcE[i]; di = dstE[i]; }
    else       { si = di = (int)(i - E); }
    int pos = atomicAdd(&cursor[di], 1);
    ssrc[pos] = si;
}

// ---- fused per-node softmax + aggregate + finalize. One wave per node. ----
// SPLIT: write cols 0..127 to out0, cols 128..255 to out1 (row stride 128).
template <int F, bool RELU, bool SPLIT>
__global__ __launch_bounds__(256) void node_agg_k(
    const int* __restrict__ rowptr, const int* __restrict__ ssrc,
    const float* __restrict__ s, const float* __restrict__ d,
    const float* __restrict__ h, const float* __restrict__ bias,
    float* __restrict__ out0, float* __restrict__ out1, int N) {
    constexpr int VPL = F / 64;  // 4 at F=256, 2 at F=128
    const int node = blockIdx.x * 4 + (threadIdx.x >> 6);
    const int lane = threadIdx.x & 63;
    if (node >= N) return;
    const int beg = rowptr[node];
    const int end = rowptr[node + 1];
    const float dn = d[node];

    // pass 1: segment max
    float mx = -1e30f;
    for (int j = beg + lane; j < end; j += 64) {
        float e = s[ssrc[j]] + dn;
        e = (e > 0.f) ? e : NEG_SLOPE * e;
        mx = fmaxf(mx, e);
    }
    #pragma unroll
    for (int off = 32; off; off >>= 1) mx = fmaxf(mx, __shfl_xor(mx, off));

    // pass 2: ex lane-parallel, broadcast via shfl, gather h[src] vectorized
    float acc[VPL] = {};
    float zsum = 0.f;
    for (int c = beg; c < end; c += 64) {
        int j = c + lane;
        float ex = 0.f;
        int sj = 0;
        if (j < end) {
            sj = ssrc[j];
            float e = s[sj] + dn;
            e = (e > 0.f) ? e : NEG_SLOPE * e;
            ex = __expf(e - mx);
        }
        zsum += ex;
        const int cnt = min(64, end - c);
        for (int kk = 0; kk < cnt; ++kk) {
            float exj = __shfl(ex, kk);
            int srcj = __shfl(sj, kk);
            const float* hp = h + (size_t)srcj * F + lane * VPL;
            if constexpr (VPL == 4) {
                float4 v = *(const float4*)hp;
                acc[0] += exj * v.x; acc[1] += exj * v.y;
                acc[2] += exj * v.z; acc[3] += exj * v.w;
            } else {
                float2 v = *(const float2*)hp;
                acc[0] += exj * v.x; acc[1] += exj * v.y;
            }
        }
    }
    #pragma unroll
    for (int off = 32; off; off >>= 1) zsum += __shfl_xor(zsum, off);
    const float inv = 1.f / zsum;

    float* op;
    if constexpr (SPLIT) {
        op = (lane < 32) ? out0 + (size_t)node * 128 + lane * VPL
                         : out1 + (size_t)node * 128 + lane * VPL - 128;
    } else {
        op = out0 + (size_t)node * F + lane * VPL;
    }
    #pragma unroll
    for (int q = 0; q < VPL; ++q) {
        float v = acc[q] * inv + bias[lane * VPL + q];
        if (RELU) v = fmaxf(v, 0.f);
        op[q] = v;
    }
}

extern "C" void kernel_launch(void* const* d_in, const int* in_sizes, int n_in,
                              void* d_out, int out_size, void* d_ws, size_t ws_size,
                              hipStream_t stream) {
    const float* x      = (const float*)d_in[0];
    const int*   eidx   = (const int*)d_in[1];
    const float* W1     = (const float*)d_in[2];
    const float* a_src1 = (const float*)d_in[3];
    const float* a_dst1 = (const float*)d_in[4];
    const float* b1     = (const float*)d_in[5];
    const float* W2     = (const float*)d_in[6];
    const float* a_src2 = (const float*)d_in[7];
    const float* a_dst2 = (const float*)d_in[8];
    const float* b2     = (const float*)d_in[9];

    const int N = in_sizes[0] / 128;   // 50000
    const int E = in_sizes[1] / 2;     // 800000
    const int F_IN = 128, H = 256, F_OUT = 128;
    const long long EA = (long long)E + N;

    const int* srcE = eidx;
    const int* dstE = eidx + E;

    // ---- workspace layout (~81 MB) ----
    float* bufA   = (float*)d_ws;                  // N*256: h1; later h2 (N*128)
    float* g1b    = bufA + (size_t)N * H;          // N*128: g1 cols 128..255
    float* sbuf   = g1b + (size_t)N * 128;         // N
    float* dbuf   = sbuf + N;                      // N
    int*   rowptr = (int*)(dbuf + N);              // N+1
    int*   cnt    = rowptr + (N + 1);              // N (doubles as cursor)
    int*   ssrc   = cnt + N;                       // E+N

    float* out = (float*)d_out;
    float* g1a = out;                              // g1 cols 0..127 (scratch)

    // ---------------- CSR build (shared by both layers) ----------------
    {
        hipMemsetAsync(cnt, 0, (size_t)N * 4, stream);
        int eb = (int)((EA + 255) / 256);
        hist_k<<<eb, 256, 0, stream>>>(dstE, cnt, E, N);
        exscan_k<<<1, 1024, 0, stream>>>(cnt, rowptr, N);
        scatter_k<<<eb, 256, 0, stream>>>(srcE, dstE, cnt, ssrc, E, N);
    }

    // ---------------- layer 1 (128 -> 256, relu) ----------------
    {
        dim3 g1(H / 64, (N + 63) / 64);
        gemm_f32<<<g1, 256, 0, stream>>>(x, x, W1, bufA, N, F_IN, H);

        int rb = (N * 64 + 255) / 256;
        rowdot_k<256><<<rb, 256, 0, stream>>>(bufA, a_src1, a_dst1, sbuf, dbuf, N);

        int nb = (N + 3) / 4;
        node_agg_k<256, true, true><<<nb, 256, 0, stream>>>(
            rowptr, ssrc, sbuf, dbuf, bufA, b1, g1a, g1b, N);
    }

    // ---------------- layer 2 (256 -> 128) ----------------
    {
        float* h2 = bufA;  // h1 dead; h2 is N*128
        dim3 g2(F_OUT / 64, (N + 63) / 64);
        gemm_f32<<<g2, 256, 0, stream>>>(g1a, g1b, W2, h2, N, H, F_OUT);

        int rb = (N * 64 + 255) / 256;
        rowdot_k<128><<<rb, 256, 0, stream>>>(h2, a_src2, a_dst2, sbuf, dbuf, N);

        int nb = (N + 3) / 4;
        node_agg_k<128, false, false><<<nb, 256, 0, stream>>>(
            rowptr, ssrc, sbuf, dbuf, h2, b2, out, nullptr, N);
    }
}

// Round 4
// 493.627 us; speedup vs baseline: 9.3789x; 1.1706x over previous
//
#include <hip/hip_runtime.h>
#include <hip/hip_bf16.h>

// ---------------------------------------------------------------------------
// GAT encoder, 2 layers. Round 4: CSR-gather aggregation (round-3 structure)
// + bf16 MFMA GEMMs with split-precision (hi/lo bf16, 3-term) so GEMM error
// stays at f32 level. g1 is produced directly as bf16 hi/lo by node_agg1's
// epilogue (hi in ws, lo in d_out used as scratch). ws stays ~81MB.
// ---------------------------------------------------------------------------

#define NEG_SLOPE 0.2f

typedef __attribute__((ext_vector_type(8))) short bf16x8;
typedef __attribute__((ext_vector_type(4))) float f32x4;

__device__ __forceinline__ unsigned short f2bf(float v) {
    __hip_bfloat16 b = __float2bfloat16(v);
    return *reinterpret_cast<unsigned short*>(&b);
}
__device__ __forceinline__ float bf2f(unsigned short u) {
    __hip_bfloat16 b = *reinterpret_cast<__hip_bfloat16*>(&u);
    return __bfloat162float(b);
}

// ---- split f32 stream into hi/lo bf16 (vectorized float4 -> ushort4 x2) ----
__global__ __launch_bounds__(256) void split_k(
    const float4* __restrict__ in, ushort4* __restrict__ hi,
    ushort4* __restrict__ lo, long n4) {
    long i = (long)blockIdx.x * 256 + threadIdx.x;
    if (i >= n4) return;
    float4 v = in[i];
    ushort4 h, l;
    h.x = f2bf(v.x); l.x = f2bf(v.x - bf2f(h.x));
    h.y = f2bf(v.y); l.y = f2bf(v.y - bf2f(h.y));
    h.z = f2bf(v.z); l.z = f2bf(v.z - bf2f(h.z));
    h.w = f2bf(v.w); l.w = f2bf(v.w - bf2f(h.w));
    hi[i] = h; lo[i] = l;
}

// ---- weight transpose + split: W[K][Nn] f32 -> WT hi/lo [Nn][K] bf16 ----
__global__ __launch_bounds__(256) void wsplit_t_k(
    const float* __restrict__ W, unsigned short* __restrict__ hiT,
    unsigned short* __restrict__ loT, int K, int Nn) {
    int i = blockIdx.x * 256 + threadIdx.x;
    if (i >= K * Nn) return;
    int k = i / Nn, n = i - k * Nn;
    float v = W[i];
    unsigned short h = f2bf(v);
    unsigned short l = f2bf(v - bf2f(h));
    hiT[(size_t)n * K + k] = h;
    loT[(size_t)n * K + k] = l;
}

// ---- split-precision bf16 MFMA GEMM: C[M][NN] f32 = A @ B ----
// A as hi/lo [M][K] bf16 bits; B as hi/lo TRANSPOSED [NN][K] bf16 bits.
// Block: 256 thr = 4 waves; tile BM=128, BN=64, BK=32. Wave w owns rows
// [w*32, w*32+32) of the tile as 2x4 frags of 16x16 (MFMA 16x16x32 bf16).
template <int K, int NN>
__global__ __launch_bounds__(256) void gemm_split_mfma(
    const unsigned short* __restrict__ Ahi, const unsigned short* __restrict__ Alo,
    const unsigned short* __restrict__ BThi, const unsigned short* __restrict__ BTlo,
    float* __restrict__ C, int M) {
    constexpr int BK = 32, PAD = 8;
    __shared__ short As[2][128][BK + PAD];  // [hi/lo][row][k]
    __shared__ short Bs[2][64][BK + PAD];   // [hi/lo][col][k]
    const int tid = threadIdx.x;
    const int wv = tid >> 6;
    const int ln = tid & 63;
    const int row0 = blockIdx.x * 128;
    const int col0 = blockIdx.y * 64;

    f32x4 acc[2][4];
    #pragma unroll
    for (int m = 0; m < 2; ++m)
        #pragma unroll
        for (int n = 0; n < 4; ++n) acc[m][n] = {0.f, 0.f, 0.f, 0.f};

    const int l15 = ln & 15;
    const int kg = (ln >> 4) * 8;

    for (int k0 = 0; k0 < K; k0 += BK) {
        // stage A (hi,lo): 128x32 each; 512 vec8 per matrix, 2 per thread
        #pragma unroll
        for (int s = 0; s < 2; ++s) {
            const unsigned short* Ap = s ? Alo : Ahi;
            #pragma unroll
            for (int t = 0; t < 2; ++t) {
                int v = tid + t * 256;
                int r = v >> 2;
                int kc = (v & 3) * 8;
                bf16x8 val = {0, 0, 0, 0, 0, 0, 0, 0};
                int gr = row0 + r;
                if (gr < M)
                    val = *(const bf16x8*)(Ap + (size_t)gr * K + k0 + kc);
                *(bf16x8*)(&As[s][r][kc]) = val;
            }
        }
        // stage B (hi,lo): 64x32 each; 256 vec8 per matrix, 1 per thread
        #pragma unroll
        for (int s = 0; s < 2; ++s) {
            const unsigned short* Bp = s ? BTlo : BThi;
            int c = tid >> 2;
            int kc = (tid & 3) * 8;
            *(bf16x8*)(&Bs[s][c][kc]) =
                *(const bf16x8*)(Bp + (size_t)(col0 + c) * K + k0 + kc);
        }
        __syncthreads();

        bf16x8 ah[2], al[2], bh[4], bl[4];
        #pragma unroll
        for (int m = 0; m < 2; ++m) {
            ah[m] = *(const bf16x8*)&As[0][wv * 32 + m * 16 + l15][kg];
            al[m] = *(const bf16x8*)&As[1][wv * 32 + m * 16 + l15][kg];
        }
        #pragma unroll
        for (int n = 0; n < 4; ++n) {
            bh[n] = *(const bf16x8*)&Bs[0][n * 16 + l15][kg];
            bl[n] = *(const bf16x8*)&Bs[1][n * 16 + l15][kg];
        }
        #pragma unroll
        for (int m = 0; m < 2; ++m)
            #pragma unroll
            for (int n = 0; n < 4; ++n) {
                acc[m][n] = __builtin_amdgcn_mfma_f32_16x16x32_bf16(
                    ah[m], bh[n], acc[m][n], 0, 0, 0);
                acc[m][n] = __builtin_amdgcn_mfma_f32_16x16x32_bf16(
                    ah[m], bl[n], acc[m][n], 0, 0, 0);
                acc[m][n] = __builtin_amdgcn_mfma_f32_16x16x32_bf16(
                    al[m], bh[n], acc[m][n], 0, 0, 0);
            }
        __syncthreads();
    }

    // epilogue: C/D layout col=lane&15, row=(lane>>4)*4+reg
    const int crow = (ln >> 4) * 4;
    #pragma unroll
    for (int m = 0; m < 2; ++m) {
        #pragma unroll
        for (int n = 0; n < 4; ++n) {
            int gr0 = row0 + wv * 32 + m * 16 + crow;
            int gc = col0 + n * 16 + l15;
            #pragma unroll
            for (int q = 0; q < 4; ++q) {
                int gr = gr0 + q;
                if (gr < M) C[(size_t)gr * NN + gc] = acc[m][n][q];
            }
        }
    }
}

// ---- per-node dots: s[n] = h[n,:]·a_src, d[n] = h[n,:]·a_dst ----
template <int F>
__global__ __launch_bounds__(256) void rowdot_k(
    const float* __restrict__ h, const float* __restrict__ a_src,
    const float* __restrict__ a_dst, float* __restrict__ s,
    float* __restrict__ d, int N) {
    int w = (blockIdx.x * 256 + threadIdx.x) >> 6;
    int lane = threadIdx.x & 63;
    if (w >= N) return;
    const float* hp = h + (size_t)w * F;
    float ss = 0.f, dd = 0.f;
    #pragma unroll
    for (int f = lane; f < F; f += 64) {
        float v = hp[f];
        ss += v * a_src[f];
        dd += v * a_dst[f];
    }
    #pragma unroll
    for (int off = 32; off; off >>= 1) {
        ss += __shfl_down(ss, off);
        dd += __shfl_down(dd, off);
    }
    if (lane == 0) { s[w] = ss; d[w] = dd; }
}

// ---- CSR build ----
__global__ __launch_bounds__(256) void hist_k(
    const int* __restrict__ dstE, int* __restrict__ cnt, int E, int N) {
    long long i = (long long)blockIdx.x * 256 + threadIdx.x;
    if (i >= (long long)E + N) return;
    int di = (i < E) ? dstE[i] : (int)(i - E);
    atomicAdd(&cnt[di], 1);
}

__global__ __launch_bounds__(1024) void exscan_k(
    int* __restrict__ cnt, int* __restrict__ rowptr, int N) {
    __shared__ int sums[1024];
    const int t = threadIdx.x;
    const int chunk = (N + 1023) / 1024;
    const int begin = t * chunk;
    const int end = min(begin + chunk, N);
    int s = 0;
    for (int i = begin; i < end; ++i) s += cnt[i];
    sums[t] = s;
    __syncthreads();
    for (int off = 1; off < 1024; off <<= 1) {
        int v = (t >= off) ? sums[t - off] : 0;
        __syncthreads();
        sums[t] += v;
        __syncthreads();
    }
    int base = (t == 0) ? 0 : sums[t - 1];
    for (int i = begin; i < end; ++i) {
        int c = cnt[i];
        rowptr[i] = base;
        cnt[i] = base;  // cnt becomes the scatter cursor
        base += c;
    }
    if (t == 1023) rowptr[N] = base;
}

__global__ __launch_bounds__(256) void scatter_k(
    const int* __restrict__ srcE, const int* __restrict__ dstE,
    int* __restrict__ cursor, int* __restrict__ ssrc, int E, int N) {
    long long i = (long long)blockIdx.x * 256 + threadIdx.x;
    if (i >= (long long)E + N) return;
    int si, di;
    if (i < E) { si = srcE[i]; di = dstE[i]; }
    else       { si = di = (int)(i - E); }
    int pos = atomicAdd(&cursor[di], 1);
    ssrc[pos] = si;
}

// ---- fused per-node softmax + aggregate + finalize. One wave per node. ----
// BF16OUT: write hi/lo bf16 split (for feeding the next MFMA GEMM).
template <int F, bool RELU, bool BF16OUT>
__global__ __launch_bounds__(256) void node_agg_k(
    const int* __restrict__ rowptr, const int* __restrict__ ssrc,
    const float* __restrict__ s, const float* __restrict__ d,
    const float* __restrict__ h, const float* __restrict__ bias,
    float* __restrict__ outf, unsigned short* __restrict__ ohi,
    unsigned short* __restrict__ olo, int N) {
    constexpr int VPL = F / 64;  // 4 at F=256, 2 at F=128
    const int node = blockIdx.x * 4 + (threadIdx.x >> 6);
    const int lane = threadIdx.x & 63;
    if (node >= N) return;
    const int beg = rowptr[node];
    const int end = rowptr[node + 1];
    const float dn = d[node];

    float mx = -1e30f;
    for (int j = beg + lane; j < end; j += 64) {
        float e = s[ssrc[j]] + dn;
        e = (e > 0.f) ? e : NEG_SLOPE * e;
        mx = fmaxf(mx, e);
    }
    #pragma unroll
    for (int off = 32; off; off >>= 1) mx = fmaxf(mx, __shfl_xor(mx, off));

    float acc[VPL] = {};
    float zsum = 0.f;
    for (int c = beg; c < end; c += 64) {
        int j = c + lane;
        float ex = 0.f;
        int sj = 0;
        if (j < end) {
            sj = ssrc[j];
            float e = s[sj] + dn;
            e = (e > 0.f) ? e : NEG_SLOPE * e;
            ex = __expf(e - mx);
        }
        zsum += ex;
        const int cnt = min(64, end - c);
        for (int kk = 0; kk < cnt; ++kk) {
            float exj = __shfl(ex, kk);
            int srcj = __shfl(sj, kk);
            const float* hp = h + (size_t)srcj * F + lane * VPL;
            if constexpr (VPL == 4) {
                float4 v = *(const float4*)hp;
                acc[0] += exj * v.x; acc[1] += exj * v.y;
                acc[2] += exj * v.z; acc[3] += exj * v.w;
            } else {
                float2 v = *(const float2*)hp;
                acc[0] += exj * v.x; acc[1] += exj * v.y;
            }
        }
    }
    #pragma unroll
    for (int off = 32; off; off >>= 1) zsum += __shfl_xor(zsum, off);
    const float inv = 1.f / zsum;

    float vv[VPL];
    #pragma unroll
    for (int q = 0; q < VPL; ++q) {
        float v = acc[q] * inv + bias[lane * VPL + q];
        if (RELU) v = fmaxf(v, 0.f);
        vv[q] = v;
    }
    if constexpr (BF16OUT) {
        static_assert(VPL == 4, "BF16OUT assumes F=256");
        ushort4 hw, lw;
        hw.x = f2bf(vv[0]); lw.x = f2bf(vv[0] - bf2f(hw.x));
        hw.y = f2bf(vv[1]); lw.y = f2bf(vv[1] - bf2f(hw.y));
        hw.z = f2bf(vv[2]); lw.z = f2bf(vv[2] - bf2f(hw.z));
        hw.w = f2bf(vv[3]); lw.w = f2bf(vv[3] - bf2f(hw.w));
        *(ushort4*)(ohi + (size_t)node * F + lane * VPL) = hw;
        *(ushort4*)(olo + (size_t)node * F + lane * VPL) = lw;
    } else {
        #pragma unroll
        for (int q = 0; q < VPL; ++q)
            outf[(size_t)node * F + lane * VPL + q] = vv[q];
    }
}

extern "C" void kernel_launch(void* const* d_in, const int* in_sizes, int n_in,
                              void* d_out, int out_size, void* d_ws, size_t ws_size,
                              hipStream_t stream) {
    const float* x      = (const float*)d_in[0];
    const int*   eidx   = (const int*)d_in[1];
    const float* W1     = (const float*)d_in[2];
    const float* a_src1 = (const float*)d_in[3];
    const float* a_dst1 = (const float*)d_in[4];
    const float* b1     = (const float*)d_in[5];
    const float* W2     = (const float*)d_in[6];
    const float* a_src2 = (const float*)d_in[7];
    const float* a_dst2 = (const float*)d_in[8];
    const float* b2     = (const float*)d_in[9];

    const int N = in_sizes[0] / 128;   // 50000
    const int E = in_sizes[1] / 2;     // 800000
    const int F_IN = 128, H = 256, F_OUT = 128;
    const long long EA = (long long)E + N;

    const int* srcE = eidx;
    const int* dstE = eidx + E;

    // ---- workspace layout (~81.5 MB) ----
    float*          h1    = (float*)d_ws;                          // N*256 f32
    unsigned short* g1hi  = (unsigned short*)(h1 + (size_t)N * H); // N*256 bf16
    unsigned short* xhi   = g1hi;                                  // alias: N*128
    unsigned short* xlo   = g1hi + (size_t)N * F_IN;               // N*128
    float*          sbuf  = (float*)(g1hi + (size_t)N * H);        // N
    float*          dbuf  = sbuf + N;                              // N
    unsigned short* w1hi  = (unsigned short*)(dbuf + N);           // 128*256
    unsigned short* w1lo  = w1hi + 32768;
    unsigned short* w2hi  = w1lo + 32768;
    unsigned short* w2lo  = w2hi + 32768;
    int*            rowptr = (int*)(w2lo + 32768);                 // N+1
    int*            cnt    = rowptr + (N + 1);                     // N (cursor)
    int*            ssrc   = cnt + N;                              // E+N
    unsigned short* g1lo  = (unsigned short*)d_out;                // N*256 bf16 (scratch)
    float*          h2    = h1;                                    // N*128 f32 (h1 dead)
    float*          out   = (float*)d_out;

    // ---------------- CSR build (shared by both layers) ----------------
    {
        hipMemsetAsync(cnt, 0, (size_t)N * 4, stream);
        int eb = (int)((EA + 255) / 256);
        hist_k<<<eb, 256, 0, stream>>>(dstE, cnt, E, N);
        exscan_k<<<1, 1024, 0, stream>>>(cnt, rowptr, N);
        scatter_k<<<eb, 256, 0, stream>>>(srcE, dstE, cnt, ssrc, E, N);
    }

    // ---------------- input / weight splits ----------------
    {
        long n4 = (long)N * F_IN / 4;
        split_k<<<(int)((n4 + 255) / 256), 256, 0, stream>>>(
            (const float4*)x, (ushort4*)xhi, (ushort4*)xlo, n4);
        wsplit_t_k<<<(F_IN * H + 255) / 256, 256, 0, stream>>>(W1, w1hi, w1lo, F_IN, H);
        wsplit_t_k<<<(H * F_OUT + 255) / 256, 256, 0, stream>>>(W2, w2hi, w2lo, H, F_OUT);
    }

    // ---------------- layer 1 (128 -> 256, relu) ----------------
    {
        dim3 g1((N + 127) / 128, H / 64);
        gemm_split_mfma<128, 256><<<g1, 256, 0, stream>>>(xhi, xlo, w1hi, w1lo, h1, N);

        int rb = (N * 64 + 255) / 256;
        rowdot_k<256><<<rb, 256, 0, stream>>>(h1, a_src1, a_dst1, sbuf, dbuf, N);

        int nb = (N + 3) / 4;
        node_agg_k<256, true, true><<<nb, 256, 0, stream>>>(
            rowptr, ssrc, sbuf, dbuf, h1, b1, nullptr, g1hi, g1lo, N);
    }

    // ---------------- layer 2 (256 -> 128) ----------------
    {
        dim3 g2((N + 127) / 128, F_OUT / 64);
        gemm_split_mfma<256, 128><<<g2, 256, 0, stream>>>(g1hi, g1lo, w2hi, w2lo, h2, N);

        int rb = (N * 64 + 255) / 256;
        rowdot_k<128><<<rb, 256, 0, stream>>>(h2, a_src2, a_dst2, sbuf, dbuf, N);

        int nb = (N + 3) / 4;
        node_agg_k<128, false, false><<<nb, 256, 0, stream>>>(
            rowptr, ssrc, sbuf, dbuf, h2, b2, out, nullptr, nullptr, N);
    }
}

// Round 5
// 473.991 us; speedup vs baseline: 9.7674x; 1.0414x over previous
//
#include <hip/hip_runtime.h>
#include <hip/hip_bf16.h>

// ---------------------------------------------------------------------------
// GAT encoder, 2 layers. Round 5: aggregation pushed BEFORE the GEMM in
// layer 1 (linearity: sum_alpha (x@W) = (sum_alpha x)@W; s = x·(W@a_src)).
// CSR gather, split-precision bf16 MFMA GEMMs, bias+relu+split fused in
// GEMM1 epilogue. ws ~81MB; g1lo uses d_out as scratch.
// ---------------------------------------------------------------------------

#define NEG_SLOPE 0.2f

typedef __attribute__((ext_vector_type(8))) short bf16x8;
typedef __attribute__((ext_vector_type(4))) float f32x4;

__device__ __forceinline__ unsigned short f2bf(float v) {
    __hip_bfloat16 b = __float2bfloat16(v);
    return *reinterpret_cast<unsigned short*>(&b);
}
__device__ __forceinline__ float bf2f(unsigned short u) {
    __hip_bfloat16 b = *reinterpret_cast<__hip_bfloat16*>(&u);
    return __bfloat162float(b);
}

// ---- weight transpose + split: W[K][Nn] f32 -> WT hi/lo [Nn][K] bf16 ----
__global__ __launch_bounds__(256) void wsplit_t_k(
    const float* __restrict__ W, unsigned short* __restrict__ hiT,
    unsigned short* __restrict__ loT, int K, int Nn) {
    int i = blockIdx.x * 256 + threadIdx.x;
    if (i >= K * Nn) return;
    int k = i / Nn, n = i - k * Nn;
    float v = W[i];
    unsigned short h = f2bf(v);
    unsigned short l = f2bf(v - bf2f(h));
    hiT[(size_t)n * K + k] = h;
    loT[(size_t)n * K + k] = l;
}

// ---- projected attention vectors: ws = W @ a_src, wd = W @ a_dst ----
// W: [K][Nn]; ws,wd: [K]. One block of K threads.
__global__ void proj_k(const float* __restrict__ W,
                       const float* __restrict__ a_src,
                       const float* __restrict__ a_dst,
                       float* __restrict__ ws, float* __restrict__ wd,
                       int K, int Nn) {
    int f = threadIdx.x;
    if (f >= K) return;
    const float* row = W + (size_t)f * Nn;
    float s = 0.f, d = 0.f;
    for (int j = 0; j < Nn; ++j) {
        float v = row[j];
        s += v * a_src[j];
        d += v * a_dst[j];
    }
    ws[f] = s;
    wd[f] = d;
}

// ---- split-precision bf16 MFMA GEMM: A[M][K] @ BT[NN][K] -> [M][NN] ----
// EPI=0: plain f32 store to Cf. EPI=1: v=relu(acc+bias[col]); bf16 hi/lo
// split stores to Chi/Clo. Block: 4 waves; BM=128, BN=64, BK=32;
// MFMA 16x16x32 bf16, 3-term hi/lo product.
template <int K, int NN, int EPI>
__global__ __launch_bounds__(256) void gemm_split_mfma(
    const unsigned short* __restrict__ Ahi, const unsigned short* __restrict__ Alo,
    const unsigned short* __restrict__ BThi, const unsigned short* __restrict__ BTlo,
    float* __restrict__ Cf, unsigned short* __restrict__ Chi,
    unsigned short* __restrict__ Clo, const float* __restrict__ bias, int M) {
    constexpr int BK = 32, PAD = 8;
    __shared__ short As[2][128][BK + PAD];
    __shared__ short Bs[2][64][BK + PAD];
    const int tid = threadIdx.x;
    const int wv = tid >> 6;
    const int ln = tid & 63;
    const int row0 = blockIdx.x * 128;
    const int col0 = blockIdx.y * 64;

    f32x4 acc[2][4];
    #pragma unroll
    for (int m = 0; m < 2; ++m)
        #pragma unroll
        for (int n = 0; n < 4; ++n) acc[m][n] = {0.f, 0.f, 0.f, 0.f};

    const int l15 = ln & 15;
    const int kg = (ln >> 4) * 8;

    for (int k0 = 0; k0 < K; k0 += BK) {
        #pragma unroll
        for (int s = 0; s < 2; ++s) {
            const unsigned short* Ap = s ? Alo : Ahi;
            #pragma unroll
            for (int t = 0; t < 2; ++t) {
                int v = tid + t * 256;
                int r = v >> 2;
                int kc = (v & 3) * 8;
                bf16x8 val = {0, 0, 0, 0, 0, 0, 0, 0};
                int gr = row0 + r;
                if (gr < M)
                    val = *(const bf16x8*)(Ap + (size_t)gr * K + k0 + kc);
                *(bf16x8*)(&As[s][r][kc]) = val;
            }
        }
        #pragma unroll
        for (int s = 0; s < 2; ++s) {
            const unsigned short* Bp = s ? BTlo : BThi;
            int c = tid >> 2;
            int kc = (tid & 3) * 8;
            *(bf16x8*)(&Bs[s][c][kc]) =
                *(const bf16x8*)(Bp + (size_t)(col0 + c) * K + k0 + kc);
        }
        __syncthreads();

        bf16x8 ah[2], al[2], bh[4], bl[4];
        #pragma unroll
        for (int m = 0; m < 2; ++m) {
            ah[m] = *(const bf16x8*)&As[0][wv * 32 + m * 16 + l15][kg];
            al[m] = *(const bf16x8*)&As[1][wv * 32 + m * 16 + l15][kg];
        }
        #pragma unroll
        for (int n = 0; n < 4; ++n) {
            bh[n] = *(const bf16x8*)&Bs[0][n * 16 + l15][kg];
            bl[n] = *(const bf16x8*)&Bs[1][n * 16 + l15][kg];
        }
        #pragma unroll
        for (int m = 0; m < 2; ++m)
            #pragma unroll
            for (int n = 0; n < 4; ++n) {
                acc[m][n] = __builtin_amdgcn_mfma_f32_16x16x32_bf16(
                    ah[m], bh[n], acc[m][n], 0, 0, 0);
                acc[m][n] = __builtin_amdgcn_mfma_f32_16x16x32_bf16(
                    ah[m], bl[n], acc[m][n], 0, 0, 0);
                acc[m][n] = __builtin_amdgcn_mfma_f32_16x16x32_bf16(
                    al[m], bh[n], acc[m][n], 0, 0, 0);
            }
        __syncthreads();
    }

    // epilogue: C/D layout col=lane&15, row=(lane>>4)*4+reg
    const int crow = (ln >> 4) * 4;
    #pragma unroll
    for (int m = 0; m < 2; ++m) {
        #pragma unroll
        for (int n = 0; n < 4; ++n) {
            int gr0 = row0 + wv * 32 + m * 16 + crow;
            int gc = col0 + n * 16 + l15;
            #pragma unroll
            for (int q = 0; q < 4; ++q) {
                int gr = gr0 + q;
                if (gr >= M) continue;
                if constexpr (EPI == 0) {
                    Cf[(size_t)gr * NN + gc] = acc[m][n][q];
                } else {
                    float v = acc[m][n][q] + bias[gc];
                    v = fmaxf(v, 0.f);
                    unsigned short h = f2bf(v);
                    unsigned short l = f2bf(v - bf2f(h));
                    Chi[(size_t)gr * NN + gc] = h;
                    Clo[(size_t)gr * NN + gc] = l;
                }
            }
        }
    }
}

// ---- per-node dots: s[n] = h[n,:]·va, d[n] = h[n,:]·vb ----
template <int F>
__global__ __launch_bounds__(256) void rowdot_k(
    const float* __restrict__ h, const float* __restrict__ va,
    const float* __restrict__ vb, float* __restrict__ s,
    float* __restrict__ d, int N) {
    int w = (blockIdx.x * 256 + threadIdx.x) >> 6;
    int lane = threadIdx.x & 63;
    if (w >= N) return;
    const float* hp = h + (size_t)w * F;
    float ss = 0.f, dd = 0.f;
    #pragma unroll
    for (int f = lane; f < F; f += 64) {
        float v = hp[f];
        ss += v * va[f];
        dd += v * vb[f];
    }
    #pragma unroll
    for (int off = 32; off; off >>= 1) {
        ss += __shfl_down(ss, off);
        dd += __shfl_down(dd, off);
    }
    if (lane == 0) { s[w] = ss; d[w] = dd; }
}

// ---- CSR build ----
__global__ __launch_bounds__(256) void hist_k(
    const int* __restrict__ dstE, int* __restrict__ cnt, int E, int N) {
    long long i = (long long)blockIdx.x * 256 + threadIdx.x;
    if (i >= (long long)E + N) return;
    int di = (i < E) ? dstE[i] : (int)(i - E);
    atomicAdd(&cnt[di], 1);
}

__global__ __launch_bounds__(1024) void exscan_k(
    int* __restrict__ cnt, int* __restrict__ rowptr, int N) {
    __shared__ int sums[1024];
    const int t = threadIdx.x;
    const int chunk = (N + 1023) / 1024;
    const int begin = t * chunk;
    const int end = min(begin + chunk, N);
    int s = 0;
    for (int i = begin; i < end; ++i) s += cnt[i];
    sums[t] = s;
    __syncthreads();
    for (int off = 1; off < 1024; off <<= 1) {
        int v = (t >= off) ? sums[t - off] : 0;
        __syncthreads();
        sums[t] += v;
        __syncthreads();
    }
    int base = (t == 0) ? 0 : sums[t - 1];
    for (int i = begin; i < end; ++i) {
        int c = cnt[i];
        rowptr[i] = base;
        cnt[i] = base;  // cnt becomes the scatter cursor
        base += c;
    }
    if (t == 1023) rowptr[N] = base;
}

__global__ __launch_bounds__(256) void scatter_k(
    const int* __restrict__ srcE, const int* __restrict__ dstE,
    int* __restrict__ cursor, int* __restrict__ ssrc, int E, int N) {
    long long i = (long long)blockIdx.x * 256 + threadIdx.x;
    if (i >= (long long)E + N) return;
    int si, di;
    if (i < E) { si = srcE[i]; di = dstE[i]; }
    else       { si = di = (int)(i - E); }
    int pos = atomicAdd(&cursor[di], 1);
    ssrc[pos] = si;
}

// ---- fused per-node softmax + aggregate. One wave per node. F=128. ----
// BF16OUT=true : out = (sum ex·h[src])/z as bf16 hi/lo (no bias).
// BF16OUT=false: out = (sum ex·h[src])/z + bias as f32.
template <int F, bool BF16OUT>
__global__ __launch_bounds__(256) void node_agg_k(
    const int* __restrict__ rowptr, const int* __restrict__ ssrc,
    const float* __restrict__ s, const float* __restrict__ d,
    const float* __restrict__ h, const float* __restrict__ bias,
    float* __restrict__ outf, unsigned short* __restrict__ ohi,
    unsigned short* __restrict__ olo, int N) {
    constexpr int VPL = F / 64;  // 2 at F=128
    const int node = blockIdx.x * 4 + (threadIdx.x >> 6);
    const int lane = threadIdx.x & 63;
    if (node >= N) return;
    const int beg = rowptr[node];
    const int end = rowptr[node + 1];
    const float dn = d[node];

    float mx = -1e30f;
    for (int j = beg + lane; j < end; j += 64) {
        float e = s[ssrc[j]] + dn;
        e = (e > 0.f) ? e : NEG_SLOPE * e;
        mx = fmaxf(mx, e);
    }
    #pragma unroll
    for (int off = 32; off; off >>= 1) mx = fmaxf(mx, __shfl_xor(mx, off));

    float acc[VPL] = {};
    float zsum = 0.f;
    for (int c = beg; c < end; c += 64) {
        int j = c + lane;
        float ex = 0.f;
        int sj = 0;
        if (j < end) {
            sj = ssrc[j];
            float e = s[sj] + dn;
            e = (e > 0.f) ? e : NEG_SLOPE * e;
            ex = __expf(e - mx);
        }
        zsum += ex;
        const int cnt = min(64, end - c);
        for (int kk = 0; kk < cnt; ++kk) {
            float exj = __shfl(ex, kk);
            int srcj = __shfl(sj, kk);
            const float* hp = h + (size_t)srcj * F + lane * VPL;
            if constexpr (VPL == 4) {
                float4 v = *(const float4*)hp;
                acc[0] += exj * v.x; acc[1] += exj * v.y;
                acc[2] += exj * v.z; acc[3] += exj * v.w;
            } else {
                float2 v = *(const float2*)hp;
                acc[0] += exj * v.x; acc[1] += exj * v.y;
            }
        }
    }
    #pragma unroll
    for (int off = 32; off; off >>= 1) zsum += __shfl_xor(zsum, off);
    const float inv = 1.f / zsum;

    if constexpr (BF16OUT) {
        static_assert(VPL == 2);
        float v0 = acc[0] * inv, v1 = acc[1] * inv;
        ushort2 hw, lw;
        hw.x = f2bf(v0); lw.x = f2bf(v0 - bf2f(hw.x));
        hw.y = f2bf(v1); lw.y = f2bf(v1 - bf2f(hw.y));
        *(ushort2*)(ohi + (size_t)node * F + lane * VPL) = hw;
        *(ushort2*)(olo + (size_t)node * F + lane * VPL) = lw;
    } else {
        #pragma unroll
        for (int q = 0; q < VPL; ++q)
            outf[(size_t)node * F + lane * VPL + q] =
                acc[q] * inv + bias[lane * VPL + q];
    }
}

extern "C" void kernel_launch(void* const* d_in, const int* in_sizes, int n_in,
                              void* d_out, int out_size, void* d_ws, size_t ws_size,
                              hipStream_t stream) {
    const float* x      = (const float*)d_in[0];
    const int*   eidx   = (const int*)d_in[1];
    const float* W1     = (const float*)d_in[2];
    const float* a_src1 = (const float*)d_in[3];
    const float* a_dst1 = (const float*)d_in[4];
    const float* b1     = (const float*)d_in[5];
    const float* W2     = (const float*)d_in[6];
    const float* a_src2 = (const float*)d_in[7];
    const float* a_dst2 = (const float*)d_in[8];
    const float* b2     = (const float*)d_in[9];

    const int N = in_sizes[0] / 128;   // 50000
    const int E = in_sizes[1] / 2;     // 800000
    const int F_IN = 128, H = 256, F_OUT = 128;
    const long long EA = (long long)E + N;

    const int* srcE = eidx;
    const int* dstE = eidx + E;

    // ---- workspace layout (~81 MB) ----
    unsigned short* aggxhi = (unsigned short*)d_ws;                 // N*128 bf16
    unsigned short* aggxlo = aggxhi + (size_t)N * F_IN;             // N*128 bf16
    unsigned short* g1hi   = aggxlo + (size_t)N * F_IN;             // N*256 bf16
    float*          h2     = (float*)(g1hi + (size_t)N * H);        // N*128 f32
    float*          sbuf   = h2 + (size_t)N * F_OUT;                // N
    float*          dbuf   = sbuf + N;                              // N
    float*          w_s1   = dbuf + N;                              // 128
    float*          w_d1   = w_s1 + F_IN;                           // 128
    unsigned short* w1hi   = (unsigned short*)(w_d1 + F_IN);        // 128*256
    unsigned short* w1lo   = w1hi + 32768;
    unsigned short* w2hi   = w1lo + 32768;
    unsigned short* w2lo   = w2hi + 32768;
    int*            rowptr = (int*)(w2lo + 32768);                  // N+1
    int*            cnt    = rowptr + (N + 1);                      // N (cursor)
    int*            ssrc   = cnt + N;                               // E+N

    unsigned short* g1lo   = (unsigned short*)d_out;                // N*256 bf16 (scratch)
    float*          out    = (float*)d_out;

    // ---------------- CSR build ----------------
    {
        hipMemsetAsync(cnt, 0, (size_t)N * 4, stream);
        int eb = (int)((EA + 255) / 256);
        hist_k<<<eb, 256, 0, stream>>>(dstE, cnt, E, N);
        exscan_k<<<1, 1024, 0, stream>>>(cnt, rowptr, N);
        scatter_k<<<eb, 256, 0, stream>>>(srcE, dstE, cnt, ssrc, E, N);
    }

    // ---------------- weight prep ----------------
    proj_k<<<1, 128, 0, stream>>>(W1, a_src1, a_dst1, w_s1, w_d1, F_IN, H);
    wsplit_t_k<<<(F_IN * H + 255) / 256, 256, 0, stream>>>(W1, w1hi, w1lo, F_IN, H);
    wsplit_t_k<<<(H * F_OUT + 255) / 256, 256, 0, stream>>>(W2, w2hi, w2lo, H, F_OUT);

    // ---------------- layer 1 (aggregate x, then GEMM) ----------------
    {
        int rb = (N * 64 + 255) / 256;
        rowdot_k<128><<<rb, 256, 0, stream>>>(x, w_s1, w_d1, sbuf, dbuf, N);

        int nb = (N + 3) / 4;
        node_agg_k<128, true><<<nb, 256, 0, stream>>>(
            rowptr, ssrc, sbuf, dbuf, x, nullptr, nullptr, aggxhi, aggxlo, N);

        dim3 g1((N + 127) / 128, H / 64);
        gemm_split_mfma<128, 256, 1><<<g1, 256, 0, stream>>>(
            aggxhi, aggxlo, w1hi, w1lo, nullptr, g1hi, g1lo, b1, N);
    }

    // ---------------- layer 2 (GEMM, then aggregate h2) ----------------
    {
        dim3 g2((N + 127) / 128, F_OUT / 64);
        gemm_split_mfma<256, 128, 0><<<g2, 256, 0, stream>>>(
            g1hi, g1lo, w2hi, w2lo, h2, nullptr, nullptr, nullptr, N);

        int rb = (N * 64 + 255) / 256;
        rowdot_k<128><<<rb, 256, 0, stream>>>(h2, a_src2, a_dst2, sbuf, dbuf, N);

        int nb = (N + 3) / 4;
        node_agg_k<128, false><<<nb, 256, 0, stream>>>(
            rowptr, ssrc, sbuf, dbuf, h2, b2, out, nullptr, nullptr, N);
    }
}

// Round 6
// 381.484 us; speedup vs baseline: 12.1359x; 1.2425x over previous
//
#include <hip/hip_runtime.h>
#include <hip/hip_bf16.h>

// ---------------------------------------------------------------------------
// GAT encoder, 2 layers. Round 6: round-5 structure (agg-before-GEMM in
// layer 1, split-precision bf16 MFMA GEMMs) + multi-block 3-phase scan
// replacing the 111us single-block exscan.
// ---------------------------------------------------------------------------

#define NEG_SLOPE 0.2f
#define SCAN_SEG 2048

typedef __attribute__((ext_vector_type(8))) short bf16x8;
typedef __attribute__((ext_vector_type(4))) float f32x4;

__device__ __forceinline__ unsigned short f2bf(float v) {
    __hip_bfloat16 b = __float2bfloat16(v);
    return *reinterpret_cast<unsigned short*>(&b);
}
__device__ __forceinline__ float bf2f(unsigned short u) {
    __hip_bfloat16 b = *reinterpret_cast<__hip_bfloat16*>(&u);
    return __bfloat162float(b);
}

// ---- weight transpose + split: W[K][Nn] f32 -> WT hi/lo [Nn][K] bf16 ----
__global__ __launch_bounds__(256) void wsplit_t_k(
    const float* __restrict__ W, unsigned short* __restrict__ hiT,
    unsigned short* __restrict__ loT, int K, int Nn) {
    int i = blockIdx.x * 256 + threadIdx.x;
    if (i >= K * Nn) return;
    int k = i / Nn, n = i - k * Nn;
    float v = W[i];
    unsigned short h = f2bf(v);
    unsigned short l = f2bf(v - bf2f(h));
    hiT[(size_t)n * K + k] = h;
    loT[(size_t)n * K + k] = l;
}

// ---- projected attention vectors: ws = W @ a_src, wd = W @ a_dst ----
__global__ void proj_k(const float* __restrict__ W,
                       const float* __restrict__ a_src,
                       const float* __restrict__ a_dst,
                       float* __restrict__ ws, float* __restrict__ wd,
                       int K, int Nn) {
    int f = threadIdx.x;
    if (f >= K) return;
    const float* row = W + (size_t)f * Nn;
    float s = 0.f, d = 0.f;
    for (int j = 0; j < Nn; ++j) {
        float v = row[j];
        s += v * a_src[j];
        d += v * a_dst[j];
    }
    ws[f] = s;
    wd[f] = d;
}

// ---- split-precision bf16 MFMA GEMM: A[M][K] @ BT[NN][K] -> [M][NN] ----
template <int K, int NN, int EPI>
__global__ __launch_bounds__(256) void gemm_split_mfma(
    const unsigned short* __restrict__ Ahi, const unsigned short* __restrict__ Alo,
    const unsigned short* __restrict__ BThi, const unsigned short* __restrict__ BTlo,
    float* __restrict__ Cf, unsigned short* __restrict__ Chi,
    unsigned short* __restrict__ Clo, const float* __restrict__ bias, int M) {
    constexpr int BK = 32, PAD = 8;
    __shared__ short As[2][128][BK + PAD];
    __shared__ short Bs[2][64][BK + PAD];
    const int tid = threadIdx.x;
    const int wv = tid >> 6;
    const int ln = tid & 63;
    const int row0 = blockIdx.x * 128;
    const int col0 = blockIdx.y * 64;

    f32x4 acc[2][4];
    #pragma unroll
    for (int m = 0; m < 2; ++m)
        #pragma unroll
        for (int n = 0; n < 4; ++n) acc[m][n] = {0.f, 0.f, 0.f, 0.f};

    const int l15 = ln & 15;
    const int kg = (ln >> 4) * 8;

    for (int k0 = 0; k0 < K; k0 += BK) {
        #pragma unroll
        for (int s = 0; s < 2; ++s) {
            const unsigned short* Ap = s ? Alo : Ahi;
            #pragma unroll
            for (int t = 0; t < 2; ++t) {
                int v = tid + t * 256;
                int r = v >> 2;
                int kc = (v & 3) * 8;
                bf16x8 val = {0, 0, 0, 0, 0, 0, 0, 0};
                int gr = row0 + r;
                if (gr < M)
                    val = *(const bf16x8*)(Ap + (size_t)gr * K + k0 + kc);
                *(bf16x8*)(&As[s][r][kc]) = val;
            }
        }
        #pragma unroll
        for (int s = 0; s < 2; ++s) {
            const unsigned short* Bp = s ? BTlo : BThi;
            int c = tid >> 2;
            int kc = (tid & 3) * 8;
            *(bf16x8*)(&Bs[s][c][kc]) =
                *(const bf16x8*)(Bp + (size_t)(col0 + c) * K + k0 + kc);
        }
        __syncthreads();

        bf16x8 ah[2], al[2], bh[4], bl[4];
        #pragma unroll
        for (int m = 0; m < 2; ++m) {
            ah[m] = *(const bf16x8*)&As[0][wv * 32 + m * 16 + l15][kg];
            al[m] = *(const bf16x8*)&As[1][wv * 32 + m * 16 + l15][kg];
        }
        #pragma unroll
        for (int n = 0; n < 4; ++n) {
            bh[n] = *(const bf16x8*)&Bs[0][n * 16 + l15][kg];
            bl[n] = *(const bf16x8*)&Bs[1][n * 16 + l15][kg];
        }
        #pragma unroll
        for (int m = 0; m < 2; ++m)
            #pragma unroll
            for (int n = 0; n < 4; ++n) {
                acc[m][n] = __builtin_amdgcn_mfma_f32_16x16x32_bf16(
                    ah[m], bh[n], acc[m][n], 0, 0, 0);
                acc[m][n] = __builtin_amdgcn_mfma_f32_16x16x32_bf16(
                    ah[m], bl[n], acc[m][n], 0, 0, 0);
                acc[m][n] = __builtin_amdgcn_mfma_f32_16x16x32_bf16(
                    al[m], bh[n], acc[m][n], 0, 0, 0);
            }
        __syncthreads();
    }

    const int crow = (ln >> 4) * 4;
    #pragma unroll
    for (int m = 0; m < 2; ++m) {
        #pragma unroll
        for (int n = 0; n < 4; ++n) {
            int gr0 = row0 + wv * 32 + m * 16 + crow;
            int gc = col0 + n * 16 + l15;
            #pragma unroll
            for (int q = 0; q < 4; ++q) {
                int gr = gr0 + q;
                if (gr >= M) continue;
                if constexpr (EPI == 0) {
                    Cf[(size_t)gr * NN + gc] = acc[m][n][q];
                } else {
                    float v = acc[m][n][q] + bias[gc];
                    v = fmaxf(v, 0.f);
                    unsigned short h = f2bf(v);
                    unsigned short l = f2bf(v - bf2f(h));
                    Chi[(size_t)gr * NN + gc] = h;
                    Clo[(size_t)gr * NN + gc] = l;
                }
            }
        }
    }
}

// ---- per-node dots ----
template <int F>
__global__ __launch_bounds__(256) void rowdot_k(
    const float* __restrict__ h, const float* __restrict__ va,
    const float* __restrict__ vb, float* __restrict__ s,
    float* __restrict__ d, int N) {
    int w = (blockIdx.x * 256 + threadIdx.x) >> 6;
    int lane = threadIdx.x & 63;
    if (w >= N) return;
    const float* hp = h + (size_t)w * F;
    float ss = 0.f, dd = 0.f;
    #pragma unroll
    for (int f = lane; f < F; f += 64) {
        float v = hp[f];
        ss += v * va[f];
        dd += v * vb[f];
    }
    #pragma unroll
    for (int off = 32; off; off >>= 1) {
        ss += __shfl_down(ss, off);
        dd += __shfl_down(dd, off);
    }
    if (lane == 0) { s[w] = ss; d[w] = dd; }
}

// ---- CSR build: histogram ----
__global__ __launch_bounds__(256) void hist_k(
    const int* __restrict__ dstE, int* __restrict__ cnt, int E, int N) {
    long long i = (long long)blockIdx.x * 256 + threadIdx.x;
    if (i >= (long long)E + N) return;
    int di = (i < E) ? dstE[i] : (int)(i - E);
    atomicAdd(&cnt[di], 1);
}

// ---- 3-phase multi-block exclusive scan ----
__global__ __launch_bounds__(256) void scan_part_k(
    const int* __restrict__ cnt, int* __restrict__ part, int N) {
    __shared__ int wsum[4];
    const int base = blockIdx.x * SCAN_SEG;
    const int lim = min(base + SCAN_SEG, N);
    int s = 0;
    for (int i = base + threadIdx.x; i < lim; i += 256) s += cnt[i];
    #pragma unroll
    for (int off = 32; off; off >>= 1) s += __shfl_down(s, off);
    if ((threadIdx.x & 63) == 0) wsum[threadIdx.x >> 6] = s;
    __syncthreads();
    if (threadIdx.x == 0) part[blockIdx.x] = wsum[0] + wsum[1] + wsum[2] + wsum[3];
}

__global__ void scan_offsets_k(int* __restrict__ part, int nseg,
                               int* __restrict__ rowptr, int N) {
    if (threadIdx.x == 0) {
        int run = 0;
        for (int i = 0; i < nseg; ++i) { int c = part[i]; part[i] = run; run += c; }
        rowptr[N] = run;
    }
}

__global__ __launch_bounds__(256) void scan_write_k(
    int* __restrict__ cnt, int* __restrict__ rowptr,
    const int* __restrict__ part, int N) {
    __shared__ int wsum[4];
    const int tid = threadIdx.x;
    const int lane = tid & 63;
    const int wv = tid >> 6;
    const int tbase = blockIdx.x * SCAN_SEG + tid * 8;
    int local[8];
    int s = 0;
    #pragma unroll
    for (int q = 0; q < 8; ++q) {
        int idx = tbase + q;
        int c = (idx < N) ? cnt[idx] : 0;
        local[q] = s;
        s += c;
    }
    // inclusive wave scan of per-thread sums
    int incl = s;
    #pragma unroll
    for (int off = 1; off < 64; off <<= 1) {
        int t = __shfl_up(incl, off);
        if (lane >= off) incl += t;
    }
    if (lane == 63) wsum[wv] = incl;
    __syncthreads();
    if (tid == 0) {
        int r = 0;
        #pragma unroll
        for (int i = 0; i < 4; ++i) { int c = wsum[i]; wsum[i] = r; r += c; }
    }
    __syncthreads();
    const int base = part[blockIdx.x] + wsum[wv] + (incl - s);
    #pragma unroll
    for (int q = 0; q < 8; ++q) {
        int idx = tbase + q;
        if (idx < N) {
            int v = base + local[q];
            rowptr[idx] = v;
            cnt[idx] = v;  // cnt becomes the scatter cursor
        }
    }
}

// ---- CSR build: scatter ----
__global__ __launch_bounds__(256) void scatter_k(
    const int* __restrict__ srcE, const int* __restrict__ dstE,
    int* __restrict__ cursor, int* __restrict__ ssrc, int E, int N) {
    long long i = (long long)blockIdx.x * 256 + threadIdx.x;
    if (i >= (long long)E + N) return;
    int si, di;
    if (i < E) { si = srcE[i]; di = dstE[i]; }
    else       { si = di = (int)(i - E); }
    int pos = atomicAdd(&cursor[di], 1);
    ssrc[pos] = si;
}

// ---- fused per-node softmax + aggregate. One wave per node. ----
template <int F, bool BF16OUT>
__global__ __launch_bounds__(256) void node_agg_k(
    const int* __restrict__ rowptr, const int* __restrict__ ssrc,
    const float* __restrict__ s, const float* __restrict__ d,
    const float* __restrict__ h, const float* __restrict__ bias,
    float* __restrict__ outf, unsigned short* __restrict__ ohi,
    unsigned short* __restrict__ olo, int N) {
    constexpr int VPL = F / 64;
    const int node = blockIdx.x * 4 + (threadIdx.x >> 6);
    const int lane = threadIdx.x & 63;
    if (node >= N) return;
    const int beg = rowptr[node];
    const int end = rowptr[node + 1];
    const float dn = d[node];

    float mx = -1e30f;
    for (int j = beg + lane; j < end; j += 64) {
        float e = s[ssrc[j]] + dn;
        e = (e > 0.f) ? e : NEG_SLOPE * e;
        mx = fmaxf(mx, e);
    }
    #pragma unroll
    for (int off = 32; off; off >>= 1) mx = fmaxf(mx, __shfl_xor(mx, off));

    float acc[VPL] = {};
    float zsum = 0.f;
    for (int c = beg; c < end; c += 64) {
        int j = c + lane;
        float ex = 0.f;
        int sj = 0;
        if (j < end) {
            sj = ssrc[j];
            float e = s[sj] + dn;
            e = (e > 0.f) ? e : NEG_SLOPE * e;
            ex = __expf(e - mx);
        }
        zsum += ex;
        const int cnt = min(64, end - c);
        for (int kk = 0; kk < cnt; ++kk) {
            float exj = __shfl(ex, kk);
            int srcj = __shfl(sj, kk);
            const float* hp = h + (size_t)srcj * F + lane * VPL;
            if constexpr (VPL == 4) {
                float4 v = *(const float4*)hp;
                acc[0] += exj * v.x; acc[1] += exj * v.y;
                acc[2] += exj * v.z; acc[3] += exj * v.w;
            } else {
                float2 v = *(const float2*)hp;
                acc[0] += exj * v.x; acc[1] += exj * v.y;
            }
        }
    }
    #pragma unroll
    for (int off = 32; off; off >>= 1) zsum += __shfl_xor(zsum, off);
    const float inv = 1.f / zsum;

    if constexpr (BF16OUT) {
        static_assert(VPL == 2);
        float v0 = acc[0] * inv, v1 = acc[1] * inv;
        ushort2 hw, lw;
        hw.x = f2bf(v0); lw.x = f2bf(v0 - bf2f(hw.x));
        hw.y = f2bf(v1); lw.y = f2bf(v1 - bf2f(hw.y));
        *(ushort2*)(ohi + (size_t)node * F + lane * VPL) = hw;
        *(ushort2*)(olo + (size_t)node * F + lane * VPL) = lw;
    } else {
        #pragma unroll
        for (int q = 0; q < VPL; ++q)
            outf[(size_t)node * F + lane * VPL + q] =
                acc[q] * inv + bias[lane * VPL + q];
    }
}

extern "C" void kernel_launch(void* const* d_in, const int* in_sizes, int n_in,
                              void* d_out, int out_size, void* d_ws, size_t ws_size,
                              hipStream_t stream) {
    const float* x      = (const float*)d_in[0];
    const int*   eidx   = (const int*)d_in[1];
    const float* W1     = (const float*)d_in[2];
    const float* a_src1 = (const float*)d_in[3];
    const float* a_dst1 = (const float*)d_in[4];
    const float* b1     = (const float*)d_in[5];
    const float* W2     = (const float*)d_in[6];
    const float* a_src2 = (const float*)d_in[7];
    const float* a_dst2 = (const float*)d_in[8];
    const float* b2     = (const float*)d_in[9];

    const int N = in_sizes[0] / 128;   // 50000
    const int E = in_sizes[1] / 2;     // 800000
    const int F_IN = 128, H = 256, F_OUT = 128;
    const long long EA = (long long)E + N;

    const int* srcE = eidx;
    const int* dstE = eidx + E;

    // ---- workspace layout (~81 MB) ----
    unsigned short* aggxhi = (unsigned short*)d_ws;                 // N*128 bf16
    unsigned short* aggxlo = aggxhi + (size_t)N * F_IN;             // N*128 bf16
    unsigned short* g1hi   = aggxlo + (size_t)N * F_IN;             // N*256 bf16
    float*          h2     = (float*)(g1hi + (size_t)N * H);        // N*128 f32
    float*          sbuf   = h2 + (size_t)N * F_OUT;                // N
    float*          dbuf   = sbuf + N;                              // N
    float*          w_s1   = dbuf + N;                              // 128
    float*          w_d1   = w_s1 + F_IN;                           // 128
    unsigned short* w1hi   = (unsigned short*)(w_d1 + F_IN);        // 128*256
    unsigned short* w1lo   = w1hi + 32768;
    unsigned short* w2hi   = w1lo + 32768;
    unsigned short* w2lo   = w2hi + 32768;
    int*            rowptr = (int*)(w2lo + 32768);                  // N+1
    int*            cnt    = rowptr + (N + 1);                      // N (cursor)
    int*            part   = cnt + N;                               // 32
    int*            ssrc   = part + 32;                             // E+N

    unsigned short* g1lo   = (unsigned short*)d_out;                // N*256 bf16 (scratch)
    float*          out    = (float*)d_out;

    // ---------------- CSR build ----------------
    {
        hipMemsetAsync(cnt, 0, (size_t)N * 4, stream);
        int eb = (int)((EA + 255) / 256);
        hist_k<<<eb, 256, 0, stream>>>(dstE, cnt, E, N);
        int nseg = (N + SCAN_SEG - 1) / SCAN_SEG;
        scan_part_k<<<nseg, 256, 0, stream>>>(cnt, part, N);
        scan_offsets_k<<<1, 64, 0, stream>>>(part, nseg, rowptr, N);
        scan_write_k<<<nseg, 256, 0, stream>>>(cnt, rowptr, part, N);
        scatter_k<<<eb, 256, 0, stream>>>(srcE, dstE, cnt, ssrc, E, N);
    }

    // ---------------- weight prep ----------------
    proj_k<<<1, 128, 0, stream>>>(W1, a_src1, a_dst1, w_s1, w_d1, F_IN, H);
    wsplit_t_k<<<(F_IN * H + 255) / 256, 256, 0, stream>>>(W1, w1hi, w1lo, F_IN, H);
    wsplit_t_k<<<(H * F_OUT + 255) / 256, 256, 0, stream>>>(W2, w2hi, w2lo, H, F_OUT);

    // ---------------- layer 1 (aggregate x, then GEMM) ----------------
    {
        int rb = (N * 64 + 255) / 256;
        rowdot_k<128><<<rb, 256, 0, stream>>>(x, w_s1, w_d1, sbuf, dbuf, N);

        int nb = (N + 3) / 4;
        node_agg_k<128, true><<<nb, 256, 0, stream>>>(
            rowptr, ssrc, sbuf, dbuf, x, nullptr, nullptr, aggxhi, aggxlo, N);

        dim3 g1((N + 127) / 128, H / 64);
        gemm_split_mfma<128, 256, 1><<<g1, 256, 0, stream>>>(
            aggxhi, aggxlo, w1hi, w1lo, nullptr, g1hi, g1lo, b1, N);
    }

    // ---------------- layer 2 (GEMM, then aggregate h2) ----------------
    {
        dim3 g2((N + 127) / 128, F_OUT / 64);
        gemm_split_mfma<256, 128, 0><<<g2, 256, 0, stream>>>(
            g1hi, g1lo, w2hi, w2lo, h2, nullptr, nullptr, nullptr, N);

        int rb = (N * 64 + 255) / 256;
        rowdot_k<128><<<rb, 256, 0, stream>>>(h2, a_src2, a_dst2, sbuf, dbuf, N);

        int nb = (N + 3) / 4;
        node_agg_k<128, false><<<nb, 256, 0, stream>>>(
            rowptr, ssrc, sbuf, dbuf, h2, b2, out, nullptr, nullptr, N);
    }
}

// Round 7
// 309.730 us; speedup vs baseline: 14.9474x; 1.2317x over previous
//
#include <hip/hip_runtime.h>
#include <hip/hip_bf16.h>

// ---------------------------------------------------------------------------
// GAT encoder, 2 layers. Round 7: group-parallel node_agg gather (2x32-lane
// float4 groups for layer-1 f32; 4x16-lane 16B groups for layer-2 bf16),
// h2 stored as bf16 (halves layer-2 gather traffic), proj via rowdot.
// Structure otherwise = round 6 (agg-before-GEMM L1, split bf16 MFMA GEMMs,
// multi-block scan CSR).
// ---------------------------------------------------------------------------

#define NEG_SLOPE 0.2f
#define SCAN_SEG 2048

typedef __attribute__((ext_vector_type(8))) short bf16x8;
typedef __attribute__((ext_vector_type(4))) float f32x4;

__device__ __forceinline__ unsigned short f2bf(float v) {
    __hip_bfloat16 b = __float2bfloat16(v);
    return *reinterpret_cast<unsigned short*>(&b);
}
__device__ __forceinline__ float bf2f(unsigned short u) {
    __hip_bfloat16 b = *reinterpret_cast<__hip_bfloat16*>(&u);
    return __bfloat162float(b);
}

// ---- weight transpose + split: W[K][Nn] f32 -> WT hi/lo [Nn][K] bf16 ----
__global__ __launch_bounds__(256) void wsplit_t_k(
    const float* __restrict__ W, unsigned short* __restrict__ hiT,
    unsigned short* __restrict__ loT, int K, int Nn) {
    int i = blockIdx.x * 256 + threadIdx.x;
    if (i >= K * Nn) return;
    int k = i / Nn, n = i - k * Nn;
    float v = W[i];
    unsigned short h = f2bf(v);
    unsigned short l = f2bf(v - bf2f(h));
    hiT[(size_t)n * K + k] = h;
    loT[(size_t)n * K + k] = l;
}

// ---- split-precision bf16 MFMA GEMM: A[M][K] @ BT[NN][K] -> [M][NN] ----
// EPI=0: f32 store. EPI=1: relu(acc+bias) -> bf16 hi/lo. EPI=2: plain bf16.
template <int K, int NN, int EPI>
__global__ __launch_bounds__(256) void gemm_split_mfma(
    const unsigned short* __restrict__ Ahi, const unsigned short* __restrict__ Alo,
    const unsigned short* __restrict__ BThi, const unsigned short* __restrict__ BTlo,
    float* __restrict__ Cf, unsigned short* __restrict__ Chi,
    unsigned short* __restrict__ Clo, const float* __restrict__ bias, int M) {
    constexpr int BK = 32, PAD = 8;
    __shared__ short As[2][128][BK + PAD];
    __shared__ short Bs[2][64][BK + PAD];
    const int tid = threadIdx.x;
    const int wv = tid >> 6;
    const int ln = tid & 63;
    const int row0 = blockIdx.x * 128;
    const int col0 = blockIdx.y * 64;

    f32x4 acc[2][4];
    #pragma unroll
    for (int m = 0; m < 2; ++m)
        #pragma unroll
        for (int n = 0; n < 4; ++n) acc[m][n] = {0.f, 0.f, 0.f, 0.f};

    const int l15 = ln & 15;
    const int kg = (ln >> 4) * 8;

    for (int k0 = 0; k0 < K; k0 += BK) {
        #pragma unroll
        for (int s = 0; s < 2; ++s) {
            const unsigned short* Ap = s ? Alo : Ahi;
            #pragma unroll
            for (int t = 0; t < 2; ++t) {
                int v = tid + t * 256;
                int r = v >> 2;
                int kc = (v & 3) * 8;
                bf16x8 val = {0, 0, 0, 0, 0, 0, 0, 0};
                int gr = row0 + r;
                if (gr < M)
                    val = *(const bf16x8*)(Ap + (size_t)gr * K + k0 + kc);
                *(bf16x8*)(&As[s][r][kc]) = val;
            }
        }
        #pragma unroll
        for (int s = 0; s < 2; ++s) {
            const unsigned short* Bp = s ? BTlo : BThi;
            int c = tid >> 2;
            int kc = (tid & 3) * 8;
            *(bf16x8*)(&Bs[s][c][kc]) =
                *(const bf16x8*)(Bp + (size_t)(col0 + c) * K + k0 + kc);
        }
        __syncthreads();

        bf16x8 ah[2], al[2], bh[4], bl[4];
        #pragma unroll
        for (int m = 0; m < 2; ++m) {
            ah[m] = *(const bf16x8*)&As[0][wv * 32 + m * 16 + l15][kg];
            al[m] = *(const bf16x8*)&As[1][wv * 32 + m * 16 + l15][kg];
        }
        #pragma unroll
        for (int n = 0; n < 4; ++n) {
            bh[n] = *(const bf16x8*)&Bs[0][n * 16 + l15][kg];
            bl[n] = *(const bf16x8*)&Bs[1][n * 16 + l15][kg];
        }
        #pragma unroll
        for (int m = 0; m < 2; ++m)
            #pragma unroll
            for (int n = 0; n < 4; ++n) {
                acc[m][n] = __builtin_amdgcn_mfma_f32_16x16x32_bf16(
                    ah[m], bh[n], acc[m][n], 0, 0, 0);
                acc[m][n] = __builtin_amdgcn_mfma_f32_16x16x32_bf16(
                    ah[m], bl[n], acc[m][n], 0, 0, 0);
                acc[m][n] = __builtin_amdgcn_mfma_f32_16x16x32_bf16(
                    al[m], bh[n], acc[m][n], 0, 0, 0);
            }
        __syncthreads();
    }

    const int crow = (ln >> 4) * 4;
    #pragma unroll
    for (int m = 0; m < 2; ++m) {
        #pragma unroll
        for (int n = 0; n < 4; ++n) {
            int gr0 = row0 + wv * 32 + m * 16 + crow;
            int gc = col0 + n * 16 + l15;
            #pragma unroll
            for (int q = 0; q < 4; ++q) {
                int gr = gr0 + q;
                if (gr >= M) continue;
                if constexpr (EPI == 0) {
                    Cf[(size_t)gr * NN + gc] = acc[m][n][q];
                } else if constexpr (EPI == 1) {
                    float v = acc[m][n][q] + bias[gc];
                    v = fmaxf(v, 0.f);
                    unsigned short h = f2bf(v);
                    unsigned short l = f2bf(v - bf2f(h));
                    Chi[(size_t)gr * NN + gc] = h;
                    Clo[(size_t)gr * NN + gc] = l;
                } else {
                    Chi[(size_t)gr * NN + gc] = f2bf(acc[m][n][q]);
                }
            }
        }
    }
}

// ---- per-node dots (f32 source): s[n]=h[n,:]·va, d[n]=h[n,:]·vb ----
template <int F>
__global__ __launch_bounds__(256) void rowdot_k(
    const float* __restrict__ h, const float* __restrict__ va,
    const float* __restrict__ vb, float* __restrict__ s,
    float* __restrict__ d, int N) {
    int w = (blockIdx.x * 256 + threadIdx.x) >> 6;
    int lane = threadIdx.x & 63;
    if (w >= N) return;
    const float* hp = h + (size_t)w * F;
    float ss = 0.f, dd = 0.f;
    #pragma unroll
    for (int f = lane; f < F; f += 64) {
        float v = hp[f];
        ss += v * va[f];
        dd += v * vb[f];
    }
    #pragma unroll
    for (int off = 32; off; off >>= 1) {
        ss += __shfl_down(ss, off);
        dd += __shfl_down(dd, off);
    }
    if (lane == 0) { s[w] = ss; d[w] = dd; }
}

// ---- per-node dots (bf16 source, F=128) ----
__global__ __launch_bounds__(256) void rowdot_bf_k(
    const unsigned short* __restrict__ h, const float* __restrict__ va,
    const float* __restrict__ vb, float* __restrict__ s,
    float* __restrict__ d, int N) {
    int w = (blockIdx.x * 256 + threadIdx.x) >> 6;
    int lane = threadIdx.x & 63;
    if (w >= N) return;
    ushort2 u = *(const ushort2*)(h + (size_t)w * 128 + lane * 2);
    float v0 = bf2f(u.x), v1 = bf2f(u.y);
    float ss = v0 * va[lane * 2] + v1 * va[lane * 2 + 1];
    float dd = v0 * vb[lane * 2] + v1 * vb[lane * 2 + 1];
    #pragma unroll
    for (int off = 32; off; off >>= 1) {
        ss += __shfl_down(ss, off);
        dd += __shfl_down(dd, off);
    }
    if (lane == 0) { s[w] = ss; d[w] = dd; }
}

// ---- CSR build: histogram ----
__global__ __launch_bounds__(256) void hist_k(
    const int* __restrict__ dstE, int* __restrict__ cnt, int E, int N) {
    long long i = (long long)blockIdx.x * 256 + threadIdx.x;
    if (i >= (long long)E + N) return;
    int di = (i < E) ? dstE[i] : (int)(i - E);
    atomicAdd(&cnt[di], 1);
}

// ---- 3-phase multi-block exclusive scan ----
__global__ __launch_bounds__(256) void scan_part_k(
    const int* __restrict__ cnt, int* __restrict__ part, int N) {
    __shared__ int wsum[4];
    const int base = blockIdx.x * SCAN_SEG;
    const int lim = min(base + SCAN_SEG, N);
    int s = 0;
    for (int i = base + threadIdx.x; i < lim; i += 256) s += cnt[i];
    #pragma unroll
    for (int off = 32; off; off >>= 1) s += __shfl_down(s, off);
    if ((threadIdx.x & 63) == 0) wsum[threadIdx.x >> 6] = s;
    __syncthreads();
    if (threadIdx.x == 0) part[blockIdx.x] = wsum[0] + wsum[1] + wsum[2] + wsum[3];
}

__global__ void scan_offsets_k(int* __restrict__ part, int nseg,
                               int* __restrict__ rowptr, int N) {
    if (threadIdx.x == 0) {
        int run = 0;
        for (int i = 0; i < nseg; ++i) { int c = part[i]; part[i] = run; run += c; }
        rowptr[N] = run;
    }
}

__global__ __launch_bounds__(256) void scan_write_k(
    int* __restrict__ cnt, int* __restrict__ rowptr,
    const int* __restrict__ part, int N) {
    __shared__ int wsum[4];
    const int tid = threadIdx.x;
    const int lane = tid & 63;
    const int wv = tid >> 6;
    const int tbase = blockIdx.x * SCAN_SEG + tid * 8;
    int local[8];
    int s = 0;
    #pragma unroll
    for (int q = 0; q < 8; ++q) {
        int idx = tbase + q;
        int c = (idx < N) ? cnt[idx] : 0;
        local[q] = s;
        s += c;
    }
    int incl = s;
    #pragma unroll
    for (int off = 1; off < 64; off <<= 1) {
        int t = __shfl_up(incl, off);
        if (lane >= off) incl += t;
    }
    if (lane == 63) wsum[wv] = incl;
    __syncthreads();
    if (tid == 0) {
        int r = 0;
        #pragma unroll
        for (int i = 0; i < 4; ++i) { int c = wsum[i]; wsum[i] = r; r += c; }
    }
    __syncthreads();
    const int base = part[blockIdx.x] + wsum[wv] + (incl - s);
    #pragma unroll
    for (int q = 0; q < 8; ++q) {
        int idx = tbase + q;
        if (idx < N) {
            int v = base + local[q];
            rowptr[idx] = v;
            cnt[idx] = v;  // cnt becomes the scatter cursor
        }
    }
}

// ---- CSR build: scatter ----
__global__ __launch_bounds__(256) void scatter_k(
    const int* __restrict__ srcE, const int* __restrict__ dstE,
    int* __restrict__ cursor, int* __restrict__ ssrc, int E, int N) {
    long long i = (long long)blockIdx.x * 256 + threadIdx.x;
    if (i >= (long long)E + N) return;
    int si, di;
    if (i < E) { si = srcE[i]; di = dstE[i]; }
    else       { si = di = (int)(i - E); }
    int pos = atomicAdd(&cursor[di], 1);
    ssrc[pos] = si;
}

// ---- fused per-node softmax + aggregate. One wave per node, F=128. ----
// TPR lanes cooperate on one row (16B/lane); G=64/TPR edges in flight.
// SRCBF: gather bf16 rows. OUTSPLIT: write bf16 hi/lo (no bias); else
// f32 + bias (final output).
template <int TPR, bool SRCBF, bool OUTSPLIT>
__global__ __launch_bounds__(256) void node_agg_k(
    const int* __restrict__ rowptr, const int* __restrict__ ssrc,
    const float* __restrict__ s, const float* __restrict__ d,
    const void* __restrict__ hsrc, const float* __restrict__ bias,
    float* __restrict__ outf, unsigned short* __restrict__ ohi,
    unsigned short* __restrict__ olo, int N) {
    constexpr int F = 128;
    constexpr int G = 64 / TPR;
    constexpr int VPL = F / TPR;  // 4 (f32) or 8 (bf16) values per lane
    const int node = blockIdx.x * 4 + (threadIdx.x >> 6);
    const int lane = threadIdx.x & 63;
    if (node >= N) return;
    const int beg = rowptr[node];
    const int end = rowptr[node + 1];
    const float dn = d[node];

    // pass 1: segment max (lane-parallel)
    float mx = -1e30f;
    for (int j = beg + lane; j < end; j += 64) {
        float e = s[ssrc[j]] + dn;
        e = (e > 0.f) ? e : NEG_SLOPE * e;
        mx = fmaxf(mx, e);
    }
    #pragma unroll
    for (int off = 32; off; off >>= 1) mx = fmaxf(mx, __shfl_xor(mx, off));

    const int grp = lane / TPR;
    const int lr = lane % TPR;
    float acc[VPL] = {};
    float zsum = 0.f;

    for (int c = beg; c < end; c += 64) {
        int j = c + lane;
        float ex = 0.f;
        int sj = 0;
        if (j < end) {
            sj = ssrc[j];
            float e = s[sj] + dn;
            e = (e > 0.f) ? e : NEG_SLOPE * e;
            ex = __expf(e - mx);
        }
        zsum += ex;
        const int cnt = min(64, end - c);
        const int iters = (cnt + G - 1) / G;
        for (int i = 0; i < iters; ++i) {
            const int kk = grp + i * G;
            float exj = __shfl(ex, kk);
            int srcj = __shfl(sj, kk);
            if (kk < cnt) {
                if constexpr (!SRCBF) {
                    const float4 v = *(const float4*)(
                        (const float*)hsrc + (size_t)srcj * F + lr * 4);
                    acc[0] += exj * v.x; acc[1] += exj * v.y;
                    acc[2] += exj * v.z; acc[3] += exj * v.w;
                } else {
                    bf16x8 v = *(const bf16x8*)(
                        (const unsigned short*)hsrc + (size_t)srcj * F + lr * 8);
                    #pragma unroll
                    for (int q = 0; q < 8; ++q)
                        acc[q] += exj * bf2f(((unsigned short*)&v)[q]);
                }
            }
        }
    }
    #pragma unroll
    for (int off = 32; off; off >>= 1) zsum += __shfl_xor(zsum, off);
    // reduce acc across groups (feature offsets align: lr preserved)
    #pragma unroll
    for (int q = 0; q < VPL; ++q) {
        if constexpr (TPR <= 16) acc[q] += __shfl_xor(acc[q], 16);
        acc[q] += __shfl_xor(acc[q], 32);
    }
    const float inv = 1.f / zsum;

    if constexpr (OUTSPLIT) {
        // TPR==32, VPL==4: lanes 0..31 write ushort4 hi/lo
        if (lane < 32) {
            float v0 = acc[0] * inv, v1 = acc[1] * inv;
            float v2 = acc[2] * inv, v3 = acc[3] * inv;
            ushort4 hw, lw;
            hw.x = f2bf(v0); lw.x = f2bf(v0 - bf2f(hw.x));
            hw.y = f2bf(v1); lw.y = f2bf(v1 - bf2f(hw.y));
            hw.z = f2bf(v2); lw.z = f2bf(v2 - bf2f(hw.z));
            hw.w = f2bf(v3); lw.w = f2bf(v3 - bf2f(hw.w));
            *(ushort4*)(ohi + (size_t)node * F + lr * 4) = hw;
            *(ushort4*)(olo + (size_t)node * F + lr * 4) = lw;
        }
    } else {
        // TPR==16, VPL==8: lanes 0..15 write 8 floats (+bias)
        if (lane < 16) {
            float o[8];
            #pragma unroll
            for (int q = 0; q < 8; ++q)
                o[q] = acc[q] * inv + bias[lr * 8 + q];
            float* op = outf + (size_t)node * F + lr * 8;
            *(float4*)op = {o[0], o[1], o[2], o[3]};
            *(float4*)(op + 4) = {o[4], o[5], o[6], o[7]};
        }
    }
}

extern "C" void kernel_launch(void* const* d_in, const int* in_sizes, int n_in,
                              void* d_out, int out_size, void* d_ws, size_t ws_size,
                              hipStream_t stream) {
    const float* x      = (const float*)d_in[0];
    const int*   eidx   = (const int*)d_in[1];
    const float* W1     = (const float*)d_in[2];
    const float* a_src1 = (const float*)d_in[3];
    const float* a_dst1 = (const float*)d_in[4];
    const float* b1     = (const float*)d_in[5];
    const float* W2     = (const float*)d_in[6];
    const float* a_src2 = (const float*)d_in[7];
    const float* a_dst2 = (const float*)d_in[8];
    const float* b2     = (const float*)d_in[9];

    const int N = in_sizes[0] / 128;   // 50000
    const int E = in_sizes[1] / 2;     // 800000
    const int F_IN = 128, H = 256, F_OUT = 128;
    const long long EA = (long long)E + N;

    const int* srcE = eidx;
    const int* dstE = eidx + E;

    // ---- workspace layout ----
    unsigned short* aggxhi = (unsigned short*)d_ws;                 // N*128 bf16
    unsigned short* aggxlo = aggxhi + (size_t)N * F_IN;             // N*128 bf16
    unsigned short* g1hi   = aggxlo + (size_t)N * F_IN;             // N*256 bf16
    unsigned short* h2bf   = g1hi + (size_t)N * H;                  // N*128 bf16
    float*          sbuf   = (float*)(h2bf + (size_t)N * F_OUT);    // N
    float*          dbuf   = sbuf + N;                              // N
    float*          w_s1   = dbuf + N;                              // 128
    float*          w_d1   = w_s1 + F_IN;                           // 128
    unsigned short* w1hi   = (unsigned short*)(w_d1 + F_IN);        // 128*256
    unsigned short* w1lo   = w1hi + 32768;
    unsigned short* w2hi   = w1lo + 32768;
    unsigned short* w2lo   = w2hi + 32768;
    int*            rowptr = (int*)(w2lo + 32768);                  // N+1
    int*            cnt    = rowptr + (N + 1);                      // N (cursor)
    int*            part   = cnt + N;                               // 32
    int*            ssrc   = part + 32;                             // E+N

    unsigned short* g1lo   = (unsigned short*)d_out;                // N*256 bf16 (scratch)
    float*          out    = (float*)d_out;

    // ---------------- CSR build ----------------
    {
        hipMemsetAsync(cnt, 0, (size_t)N * 4, stream);
        int eb = (int)((EA + 255) / 256);
        hist_k<<<eb, 256, 0, stream>>>(dstE, cnt, E, N);
        int nseg = (N + SCAN_SEG - 1) / SCAN_SEG;
        scan_part_k<<<nseg, 256, 0, stream>>>(cnt, part, N);
        scan_offsets_k<<<1, 64, 0, stream>>>(part, nseg, rowptr, N);
        scan_write_k<<<nseg, 256, 0, stream>>>(cnt, rowptr, part, N);
        scatter_k<<<eb, 256, 0, stream>>>(srcE, dstE, cnt, ssrc, E, N);
    }

    // ---------------- weight prep ----------------
    // w_s1 = W1 @ a_src1, w_d1 = W1 @ a_dst1 via coalesced rowdot over W1 rows
    rowdot_k<256><<<32, 256, 0, stream>>>(W1, a_src1, a_dst1, w_s1, w_d1, F_IN);
    wsplit_t_k<<<(F_IN * H + 255) / 256, 256, 0, stream>>>(W1, w1hi, w1lo, F_IN, H);
    wsplit_t_k<<<(H * F_OUT + 255) / 256, 256, 0, stream>>>(W2, w2hi, w2lo, H, F_OUT);

    // ---------------- layer 1 (aggregate x, then GEMM) ----------------
    {
        int rb = (N * 64 + 255) / 256;
        rowdot_k<128><<<rb, 256, 0, stream>>>(x, w_s1, w_d1, sbuf, dbuf, N);

        int nb = (N + 3) / 4;
        node_agg_k<32, false, true><<<nb, 256, 0, stream>>>(
            rowptr, ssrc, sbuf, dbuf, x, nullptr, nullptr, aggxhi, aggxlo, N);

        dim3 g1((N + 127) / 128, H / 64);
        gemm_split_mfma<128, 256, 1><<<g1, 256, 0, stream>>>(
            aggxhi, aggxlo, w1hi, w1lo, nullptr, g1hi, g1lo, b1, N);
    }

    // ---------------- layer 2 (GEMM -> bf16 h2, then aggregate) ----------------
    {
        dim3 g2((N + 127) / 128, F_OUT / 64);
        gemm_split_mfma<256, 128, 2><<<g2, 256, 0, stream>>>(
            g1hi, g1lo, w2hi, w2lo, nullptr, h2bf, nullptr, nullptr, N);

        int rb = (N * 64 + 255) / 256;
        rowdot_bf_k<<<rb, 256, 0, stream>>>(h2bf, a_src2, a_dst2, sbuf, dbuf, N);

        int nb = (N + 3) / 4;
        node_agg_k<16, true, false><<<nb, 256, 0, stream>>>(
            rowptr, ssrc, sbuf, dbuf, h2bf, b2, out, nullptr, nullptr, N);
    }
}

// Round 8
// 257.423 us; speedup vs baseline: 17.9846x; 1.2032x over previous
//
#include <hip/hip_runtime.h>
#include <hip/hip_bf16.h>

// ---------------------------------------------------------------------------
// GAT encoder, 2 layers. Round 8: full-bf16 pipeline.
//  - no softmax max-pass (logits bounded; softmax is shift-invariant)
//  - node gather: 4 nodes/block, 4 groups x 16 lanes; each group handles one
//    edge end-to-end (logit+exp inline, 16B bf16 row slice), 2-level reduce
//  - x quantized to bf16 once; aggx/g1/h2 plain bf16; GEMMs plain 1-term
//    bf16 MFMA (16x16x32), f32 accumulate
// ---------------------------------------------------------------------------

#define NEG_SLOPE 0.2f
#define SCAN_SEG 2048

typedef __attribute__((ext_vector_type(8))) short bf16x8;
typedef __attribute__((ext_vector_type(4))) float f32x4;

__device__ __forceinline__ unsigned short f2bf(float v) {
    __hip_bfloat16 b = __float2bfloat16(v);
    return *reinterpret_cast<unsigned short*>(&b);
}
__device__ __forceinline__ float bf2f(unsigned short u) {
    __hip_bfloat16 b = *reinterpret_cast<__hip_bfloat16*>(&u);
    return __bfloat162float(b);
}

// ---- x -> bf16 (vectorized) ----
__global__ __launch_bounds__(256) void xbf_k(
    const float4* __restrict__ in, ushort4* __restrict__ o, long n4) {
    long i = (long)blockIdx.x * 256 + threadIdx.x;
    if (i >= n4) return;
    float4 v = in[i];
    ushort4 u;
    u.x = f2bf(v.x); u.y = f2bf(v.y); u.z = f2bf(v.z); u.w = f2bf(v.w);
    o[i] = u;
}

// ---- weight transpose: W[K][Nn] f32 -> WT [Nn][K] bf16 ----
__global__ __launch_bounds__(256) void wt_bf_k(
    const float* __restrict__ W, unsigned short* __restrict__ T, int K, int Nn) {
    int i = blockIdx.x * 256 + threadIdx.x;
    if (i >= K * Nn) return;
    int k = i / Nn, n = i - k * Nn;
    T[(size_t)n * K + k] = f2bf(W[i]);
}

// ---- plain bf16 MFMA GEMM: A[M][K] bf16 @ BT[NN][K] bf16 -> [M][NN] ----
// EPI=1: relu(acc+bias[col]) -> bf16. EPI=2: plain bf16.
template <int K, int NN, int EPI>
__global__ __launch_bounds__(256) void gemm_bf16(
    const unsigned short* __restrict__ A, const unsigned short* __restrict__ BT,
    unsigned short* __restrict__ C, const float* __restrict__ bias, int M) {
    constexpr int BK = 32, PAD = 8;
    __shared__ short As[128][BK + PAD];
    __shared__ short Bs[64][BK + PAD];
    const int tid = threadIdx.x;
    const int wv = tid >> 6;
    const int ln = tid & 63;
    const int row0 = blockIdx.x * 128;
    const int col0 = blockIdx.y * 64;

    f32x4 acc[2][4];
    #pragma unroll
    for (int m = 0; m < 2; ++m)
        #pragma unroll
        for (int n = 0; n < 4; ++n) acc[m][n] = {0.f, 0.f, 0.f, 0.f};

    const int l15 = ln & 15;
    const int kg = (ln >> 4) * 8;

    for (int k0 = 0; k0 < K; k0 += BK) {
        #pragma unroll
        for (int t = 0; t < 2; ++t) {
            int v = tid + t * 256;
            int r = v >> 2;
            int kc = (v & 3) * 8;
            bf16x8 val = {0, 0, 0, 0, 0, 0, 0, 0};
            int gr = row0 + r;
            if (gr < M)
                val = *(const bf16x8*)(A + (size_t)gr * K + k0 + kc);
            *(bf16x8*)(&As[r][kc]) = val;
        }
        {
            int c = tid >> 2;
            int kc = (tid & 3) * 8;
            *(bf16x8*)(&Bs[c][kc]) =
                *(const bf16x8*)(BT + (size_t)(col0 + c) * K + k0 + kc);
        }
        __syncthreads();

        bf16x8 ah[2], bh[4];
        #pragma unroll
        for (int m = 0; m < 2; ++m)
            ah[m] = *(const bf16x8*)&As[wv * 32 + m * 16 + l15][kg];
        #pragma unroll
        for (int n = 0; n < 4; ++n)
            bh[n] = *(const bf16x8*)&Bs[n * 16 + l15][kg];
        #pragma unroll
        for (int m = 0; m < 2; ++m)
            #pragma unroll
            for (int n = 0; n < 4; ++n)
                acc[m][n] = __builtin_amdgcn_mfma_f32_16x16x32_bf16(
                    ah[m], bh[n], acc[m][n], 0, 0, 0);
        __syncthreads();
    }

    // C/D layout: col=lane&15, row=(lane>>4)*4+reg
    const int crow = (ln >> 4) * 4;
    #pragma unroll
    for (int m = 0; m < 2; ++m) {
        #pragma unroll
        for (int n = 0; n < 4; ++n) {
            int gr0 = row0 + wv * 32 + m * 16 + crow;
            int gc = col0 + n * 16 + l15;
            #pragma unroll
            for (int q = 0; q < 4; ++q) {
                int gr = gr0 + q;
                if (gr >= M) continue;
                if constexpr (EPI == 1) {
                    float v = acc[m][n][q] + bias[gc];
                    v = fmaxf(v, 0.f);
                    C[(size_t)gr * NN + gc] = f2bf(v);
                } else {
                    C[(size_t)gr * NN + gc] = f2bf(acc[m][n][q]);
                }
            }
        }
    }
}

// ---- per-node dots (f32 source): s[n]=h[n,:]·va, d[n]=h[n,:]·vb ----
template <int F>
__global__ __launch_bounds__(256) void rowdot_k(
    const float* __restrict__ h, const float* __restrict__ va,
    const float* __restrict__ vb, float* __restrict__ s,
    float* __restrict__ d, int N) {
    int w = (blockIdx.x * 256 + threadIdx.x) >> 6;
    int lane = threadIdx.x & 63;
    if (w >= N) return;
    const float* hp = h + (size_t)w * F;
    float ss = 0.f, dd = 0.f;
    #pragma unroll
    for (int f = lane; f < F; f += 64) {
        float v = hp[f];
        ss += v * va[f];
        dd += v * vb[f];
    }
    #pragma unroll
    for (int off = 32; off; off >>= 1) {
        ss += __shfl_down(ss, off);
        dd += __shfl_down(dd, off);
    }
    if (lane == 0) { s[w] = ss; d[w] = dd; }
}

// ---- per-node dots (bf16 source, F=128) ----
__global__ __launch_bounds__(256) void rowdot_bf_k(
    const unsigned short* __restrict__ h, const float* __restrict__ va,
    const float* __restrict__ vb, float* __restrict__ s,
    float* __restrict__ d, int N) {
    int w = (blockIdx.x * 256 + threadIdx.x) >> 6;
    int lane = threadIdx.x & 63;
    if (w >= N) return;
    ushort2 u = *(const ushort2*)(h + (size_t)w * 128 + lane * 2);
    float v0 = bf2f(u.x), v1 = bf2f(u.y);
    float ss = v0 * va[lane * 2] + v1 * va[lane * 2 + 1];
    float dd = v0 * vb[lane * 2] + v1 * vb[lane * 2 + 1];
    #pragma unroll
    for (int off = 32; off; off >>= 1) {
        ss += __shfl_down(ss, off);
        dd += __shfl_down(dd, off);
    }
    if (lane == 0) { s[w] = ss; d[w] = dd; }
}

// ---- CSR build: histogram ----
__global__ __launch_bounds__(256) void hist_k(
    const int* __restrict__ dstE, int* __restrict__ cnt, int E, int N) {
    long long i = (long long)blockIdx.x * 256 + threadIdx.x;
    if (i >= (long long)E + N) return;
    int di = (i < E) ? dstE[i] : (int)(i - E);
    atomicAdd(&cnt[di], 1);
}

// ---- 3-phase multi-block exclusive scan ----
__global__ __launch_bounds__(256) void scan_part_k(
    const int* __restrict__ cnt, int* __restrict__ part, int N) {
    __shared__ int wsum[4];
    const int base = blockIdx.x * SCAN_SEG;
    const int lim = min(base + SCAN_SEG, N);
    int s = 0;
    for (int i = base + threadIdx.x; i < lim; i += 256) s += cnt[i];
    #pragma unroll
    for (int off = 32; off; off >>= 1) s += __shfl_down(s, off);
    if ((threadIdx.x & 63) == 0) wsum[threadIdx.x >> 6] = s;
    __syncthreads();
    if (threadIdx.x == 0) part[blockIdx.x] = wsum[0] + wsum[1] + wsum[2] + wsum[3];
}

__global__ void scan_offsets_k(int* __restrict__ part, int nseg,
                               int* __restrict__ rowptr, int N) {
    if (threadIdx.x == 0) {
        int run = 0;
        for (int i = 0; i < nseg; ++i) { int c = part[i]; part[i] = run; run += c; }
        rowptr[N] = run;
    }
}

__global__ __launch_bounds__(256) void scan_write_k(
    int* __restrict__ cnt, int* __restrict__ rowptr,
    const int* __restrict__ part, int N) {
    __shared__ int wsum[4];
    const int tid = threadIdx.x;
    const int lane = tid & 63;
    const int wv = tid >> 6;
    const int tbase = blockIdx.x * SCAN_SEG + tid * 8;
    int local[8];
    int s = 0;
    #pragma unroll
    for (int q = 0; q < 8; ++q) {
        int idx = tbase + q;
        int c = (idx < N) ? cnt[idx] : 0;
        local[q] = s;
        s += c;
    }
    int incl = s;
    #pragma unroll
    for (int off = 1; off < 64; off <<= 1) {
        int t = __shfl_up(incl, off);
        if (lane >= off) incl += t;
    }
    if (lane == 63) wsum[wv] = incl;
    __syncthreads();
    if (tid == 0) {
        int r = 0;
        #pragma unroll
        for (int i = 0; i < 4; ++i) { int c = wsum[i]; wsum[i] = r; r += c; }
    }
    __syncthreads();
    const int base = part[blockIdx.x] + wsum[wv] + (incl - s);
    #pragma unroll
    for (int q = 0; q < 8; ++q) {
        int idx = tbase + q;
        if (idx < N) {
            int v = base + local[q];
            rowptr[idx] = v;
            cnt[idx] = v;  // cnt becomes the scatter cursor
        }
    }
}

// ---- CSR build: scatter ----
__global__ __launch_bounds__(256) void scatter_k(
    const int* __restrict__ srcE, const int* __restrict__ dstE,
    int* __restrict__ cursor, int* __restrict__ ssrc, int E, int N) {
    long long i = (long long)blockIdx.x * 256 + threadIdx.x;
    if (i >= (long long)E + N) return;
    int si, di;
    if (i < E) { si = srcE[i]; di = dstE[i]; }
    else       { si = di = (int)(i - E); }
    int pos = atomicAdd(&cursor[di], 1);
    ssrc[pos] = si;
}

// ---- fused softmax + weighted gather. One wave/node, 4 groups x 16 lanes.
// Each group owns one edge per iteration: computes exp(leaky(s[src]+d[node]))
// inline (no max pass: logits bounded, softmax shift-invariant) and gathers
// a 16B bf16 row slice. 2-level xor reduce across groups at the end.
// OUTBF: write bf16 (aggx). else: f32 + bias (final output).
template <bool OUTBF>
__global__ __launch_bounds__(256) void node_gather_k(
    const int* __restrict__ rowptr, const int* __restrict__ ssrc,
    const float* __restrict__ s, const float* __restrict__ d,
    const unsigned short* __restrict__ hsrc, const float* __restrict__ bias,
    unsigned short* __restrict__ obf, float* __restrict__ outf, int N) {
    constexpr int F = 128, G = 4;
    const int node = blockIdx.x * 4 + (threadIdx.x >> 6);
    const int lane = threadIdx.x & 63;
    if (node >= N) return;
    const int beg = rowptr[node];
    const int end = rowptr[node + 1];
    const float dn = d[node];
    const int grp = lane >> 4;   // 0..3
    const int lr = lane & 15;    // 0..15

    float acc[8] = {};
    float zsum = 0.f;
    for (int j = beg + grp; j < end; j += G) {
        int sj = ssrc[j];                       // broadcast within group
        float e = s[sj] + dn;                   // broadcast within group
        e = (e > 0.f) ? e : NEG_SLOPE * e;
        float exj = __expf(e);
        zsum += exj;
        bf16x8 v = *(const bf16x8*)(hsrc + (size_t)sj * F + lr * 8);
        #pragma unroll
        for (int q = 0; q < 8; ++q)
            acc[q] += exj * bf2f(((unsigned short*)&v)[q]);
    }
    // reduce across the 4 groups (lanes with equal lr)
    #pragma unroll
    for (int off = 16; off < 64; off <<= 1) {
        zsum += __shfl_xor(zsum, off);
        #pragma unroll
        for (int q = 0; q < 8; ++q) acc[q] += __shfl_xor(acc[q], off);
    }
    const float inv = 1.f / zsum;

    if (lane < 16) {
        if constexpr (OUTBF) {
            bf16x8 w;
            #pragma unroll
            for (int q = 0; q < 8; ++q)
                ((unsigned short*)&w)[q] = f2bf(acc[q] * inv);
            *(bf16x8*)(obf + (size_t)node * F + lr * 8) = w;
        } else {
            float o[8];
            #pragma unroll
            for (int q = 0; q < 8; ++q)
                o[q] = acc[q] * inv + bias[lr * 8 + q];
            float* op = outf + (size_t)node * F + lr * 8;
            *(float4*)op = {o[0], o[1], o[2], o[3]};
            *(float4*)(op + 4) = {o[4], o[5], o[6], o[7]};
        }
    }
}

extern "C" void kernel_launch(void* const* d_in, const int* in_sizes, int n_in,
                              void* d_out, int out_size, void* d_ws, size_t ws_size,
                              hipStream_t stream) {
    const float* x      = (const float*)d_in[0];
    const int*   eidx   = (const int*)d_in[1];
    const float* W1     = (const float*)d_in[2];
    const float* a_src1 = (const float*)d_in[3];
    const float* a_dst1 = (const float*)d_in[4];
    const float* b1     = (const float*)d_in[5];
    const float* W2     = (const float*)d_in[6];
    const float* a_src2 = (const float*)d_in[7];
    const float* a_dst2 = (const float*)d_in[8];
    const float* b2     = (const float*)d_in[9];

    const int N = in_sizes[0] / 128;   // 50000
    const int E = in_sizes[1] / 2;     // 800000
    const int F_IN = 128, H = 256, F_OUT = 128;
    const long long EA = (long long)E + N;

    const int* srcE = eidx;
    const int* dstE = eidx + E;

    // ---- workspace layout (~69 MB) ----
    unsigned short* xbf    = (unsigned short*)d_ws;                 // N*128 bf16
    unsigned short* aggx   = xbf + (size_t)N * F_IN;                // N*128 bf16
    unsigned short* g1     = aggx + (size_t)N * F_IN;               // N*256 bf16
    unsigned short* h2bf   = g1 + (size_t)N * H;                    // N*128 bf16
    float*          sbuf   = (float*)(h2bf + (size_t)N * F_OUT);    // N
    float*          dbuf   = sbuf + N;                              // N
    float*          w_s1   = dbuf + N;                              // 128
    float*          w_d1   = w_s1 + F_IN;                           // 128
    unsigned short* w1T    = (unsigned short*)(w_d1 + F_IN);        // 256*128
    unsigned short* w2T    = w1T + 32768;                           // 128*256
    int*            rowptr = (int*)(w2T + 32768);                   // N+1
    int*            cnt    = rowptr + (N + 1);                      // N (cursor)
    int*            part   = cnt + N;                               // 32
    int*            ssrc   = part + 32;                             // E+N

    float* out = (float*)d_out;

    // ---------------- CSR build ----------------
    {
        hipMemsetAsync(cnt, 0, (size_t)N * 4, stream);
        int eb = (int)((EA + 255) / 256);
        hist_k<<<eb, 256, 0, stream>>>(dstE, cnt, E, N);
        int nseg = (N + SCAN_SEG - 1) / SCAN_SEG;
        scan_part_k<<<nseg, 256, 0, stream>>>(cnt, part, N);
        scan_offsets_k<<<1, 64, 0, stream>>>(part, nseg, rowptr, N);
        scan_write_k<<<nseg, 256, 0, stream>>>(cnt, rowptr, part, N);
        scatter_k<<<eb, 256, 0, stream>>>(srcE, dstE, cnt, ssrc, E, N);
    }

    // ---------------- prep: projections, weight transposes, x->bf16 --------
    rowdot_k<256><<<32, 256, 0, stream>>>(W1, a_src1, a_dst1, w_s1, w_d1, F_IN);
    wt_bf_k<<<(F_IN * H + 255) / 256, 256, 0, stream>>>(W1, w1T, F_IN, H);
    wt_bf_k<<<(H * F_OUT + 255) / 256, 256, 0, stream>>>(W2, w2T, H, F_OUT);
    {
        long n4 = (long)N * F_IN / 4;
        xbf_k<<<(int)((n4 + 255) / 256), 256, 0, stream>>>(
            (const float4*)x, (ushort4*)xbf, n4);
    }

    // ---------------- layer 1: rowdot -> gather(x) -> GEMM ----------------
    {
        int rb = (N * 64 + 255) / 256;
        rowdot_bf_k<<<rb, 256, 0, stream>>>(xbf, w_s1, w_d1, sbuf, dbuf, N);

        int nb = (N + 3) / 4;
        node_gather_k<true><<<nb, 256, 0, stream>>>(
            rowptr, ssrc, sbuf, dbuf, xbf, nullptr, aggx, nullptr, N);

        dim3 gg((N + 127) / 128, H / 64);
        gemm_bf16<128, 256, 1><<<gg, 256, 0, stream>>>(aggx, w1T, g1, b1, N);
    }

    // ---------------- layer 2: GEMM -> rowdot -> gather(h2) ----------------
    {
        dim3 gg((N + 127) / 128, F_OUT / 64);
        gemm_bf16<256, 128, 2><<<gg, 256, 0, stream>>>(g1, w2T, h2bf, nullptr, N);

        int rb = (N * 64 + 255) / 256;
        rowdot_bf_k<<<rb, 256, 0, stream>>>(h2bf, a_src2, a_dst2, sbuf, dbuf, N);

        int nb = (N + 3) / 4;
        node_gather_k<false><<<nb, 256, 0, stream>>>(
            rowptr, ssrc, sbuf, dbuf, h2bf, b2, nullptr, out, N);
    }
}

// Round 9
// 215.350 us; speedup vs baseline: 21.4983x; 1.1954x over previous
//
#include <hip/hip_runtime.h>
#include <hip/hip_bf16.h>

// ---------------------------------------------------------------------------
// GAT encoder, 2 layers. Round 9: round-8 full-bf16 pipeline + restructured
// CSR build: single batched returning-atomic rank pass (merges histogram),
// then scan, then atomic-free placement. No more 58us scatter.
// ---------------------------------------------------------------------------

#define NEG_SLOPE 0.2f
#define SCAN_SEG 2048

typedef __attribute__((ext_vector_type(8))) short bf16x8;
typedef __attribute__((ext_vector_type(4))) float f32x4;

__device__ __forceinline__ unsigned short f2bf(float v) {
    __hip_bfloat16 b = __float2bfloat16(v);
    return *reinterpret_cast<unsigned short*>(&b);
}
__device__ __forceinline__ float bf2f(unsigned short u) {
    __hip_bfloat16 b = *reinterpret_cast<__hip_bfloat16*>(&u);
    return __bfloat162float(b);
}

// ---- x -> bf16 (vectorized) ----
__global__ __launch_bounds__(256) void xbf_k(
    const float4* __restrict__ in, ushort4* __restrict__ o, long n4) {
    long i = (long)blockIdx.x * 256 + threadIdx.x;
    if (i >= n4) return;
    float4 v = in[i];
    ushort4 u;
    u.x = f2bf(v.x); u.y = f2bf(v.y); u.z = f2bf(v.z); u.w = f2bf(v.w);
    o[i] = u;
}

// ---- weight transpose: W[K][Nn] f32 -> WT [Nn][K] bf16 ----
__global__ __launch_bounds__(256) void wt_bf_k(
    const float* __restrict__ W, unsigned short* __restrict__ T, int K, int Nn) {
    int i = blockIdx.x * 256 + threadIdx.x;
    if (i >= K * Nn) return;
    int k = i / Nn, n = i - k * Nn;
    T[(size_t)n * K + k] = f2bf(W[i]);
}

// ---- plain bf16 MFMA GEMM: A[M][K] bf16 @ BT[NN][K] bf16 -> [M][NN] ----
// EPI=1: relu(acc+bias[col]) -> bf16. EPI=2: plain bf16.
template <int K, int NN, int EPI>
__global__ __launch_bounds__(256) void gemm_bf16(
    const unsigned short* __restrict__ A, const unsigned short* __restrict__ BT,
    unsigned short* __restrict__ C, const float* __restrict__ bias, int M) {
    constexpr int BK = 32, PAD = 8;
    __shared__ short As[128][BK + PAD];
    __shared__ short Bs[64][BK + PAD];
    const int tid = threadIdx.x;
    const int wv = tid >> 6;
    const int ln = tid & 63;
    const int row0 = blockIdx.x * 128;
    const int col0 = blockIdx.y * 64;

    f32x4 acc[2][4];
    #pragma unroll
    for (int m = 0; m < 2; ++m)
        #pragma unroll
        for (int n = 0; n < 4; ++n) acc[m][n] = {0.f, 0.f, 0.f, 0.f};

    const int l15 = ln & 15;
    const int kg = (ln >> 4) * 8;

    for (int k0 = 0; k0 < K; k0 += BK) {
        #pragma unroll
        for (int t = 0; t < 2; ++t) {
            int v = tid + t * 256;
            int r = v >> 2;
            int kc = (v & 3) * 8;
            bf16x8 val = {0, 0, 0, 0, 0, 0, 0, 0};
            int gr = row0 + r;
            if (gr < M)
                val = *(const bf16x8*)(A + (size_t)gr * K + k0 + kc);
            *(bf16x8*)(&As[r][kc]) = val;
        }
        {
            int c = tid >> 2;
            int kc = (tid & 3) * 8;
            *(bf16x8*)(&Bs[c][kc]) =
                *(const bf16x8*)(BT + (size_t)(col0 + c) * K + k0 + kc);
        }
        __syncthreads();

        bf16x8 ah[2], bh[4];
        #pragma unroll
        for (int m = 0; m < 2; ++m)
            ah[m] = *(const bf16x8*)&As[wv * 32 + m * 16 + l15][kg];
        #pragma unroll
        for (int n = 0; n < 4; ++n)
            bh[n] = *(const bf16x8*)&Bs[n * 16 + l15][kg];
        #pragma unroll
        for (int m = 0; m < 2; ++m)
            #pragma unroll
            for (int n = 0; n < 4; ++n)
                acc[m][n] = __builtin_amdgcn_mfma_f32_16x16x32_bf16(
                    ah[m], bh[n], acc[m][n], 0, 0, 0);
        __syncthreads();
    }

    // C/D layout: col=lane&15, row=(lane>>4)*4+reg
    const int crow = (ln >> 4) * 4;
    #pragma unroll
    for (int m = 0; m < 2; ++m) {
        #pragma unroll
        for (int n = 0; n < 4; ++n) {
            int gr0 = row0 + wv * 32 + m * 16 + crow;
            int gc = col0 + n * 16 + l15;
            #pragma unroll
            for (int q = 0; q < 4; ++q) {
                int gr = gr0 + q;
                if (gr >= M) continue;
                if constexpr (EPI == 1) {
                    float v = acc[m][n][q] + bias[gc];
                    v = fmaxf(v, 0.f);
                    C[(size_t)gr * NN + gc] = f2bf(v);
                } else {
                    C[(size_t)gr * NN + gc] = f2bf(acc[m][n][q]);
                }
            }
        }
    }
}

// ---- per-node dots (f32 source): s[n]=h[n,:]·va, d[n]=h[n,:]·vb ----
template <int F>
__global__ __launch_bounds__(256) void rowdot_k(
    const float* __restrict__ h, const float* __restrict__ va,
    const float* __restrict__ vb, float* __restrict__ s,
    float* __restrict__ d, int N) {
    int w = (blockIdx.x * 256 + threadIdx.x) >> 6;
    int lane = threadIdx.x & 63;
    if (w >= N) return;
    const float* hp = h + (size_t)w * F;
    float ss = 0.f, dd = 0.f;
    #pragma unroll
    for (int f = lane; f < F; f += 64) {
        float v = hp[f];
        ss += v * va[f];
        dd += v * vb[f];
    }
    #pragma unroll
    for (int off = 32; off; off >>= 1) {
        ss += __shfl_down(ss, off);
        dd += __shfl_down(dd, off);
    }
    if (lane == 0) { s[w] = ss; d[w] = dd; }
}

// ---- per-node dots (bf16 source, F=128) ----
__global__ __launch_bounds__(256) void rowdot_bf_k(
    const unsigned short* __restrict__ h, const float* __restrict__ va,
    const float* __restrict__ vb, float* __restrict__ s,
    float* __restrict__ d, int N) {
    int w = (blockIdx.x * 256 + threadIdx.x) >> 6;
    int lane = threadIdx.x & 63;
    if (w >= N) return;
    ushort2 u = *(const ushort2*)(h + (size_t)w * 128 + lane * 2);
    float v0 = bf2f(u.x), v1 = bf2f(u.y);
    float ss = v0 * va[lane * 2] + v1 * va[lane * 2 + 1];
    float dd = v0 * vb[lane * 2] + v1 * vb[lane * 2 + 1];
    #pragma unroll
    for (int off = 32; off; off >>= 1) {
        ss += __shfl_down(ss, off);
        dd += __shfl_down(dd, off);
    }
    if (lane == 0) { s[w] = ss; d[w] = dd; }
}

// ---- CSR build pass A: rank = within-dst arrival order; cnt = histogram ----
// VPT edges per thread (grid-slice layout keeps every load coalesced); the
// VPT returning atomics are independent -> issued back-to-back.
#define RANK_VPT 8
__global__ __launch_bounds__(256) void rank_k(
    const int* __restrict__ dstE, int* __restrict__ cnt,
    int* __restrict__ rank, int E, int N, int stride) {
    const int i0 = blockIdx.x * 256 + threadIdx.x;
    const int total = E + N;
    int idx[RANK_VPT], di[RANK_VPT], r[RANK_VPT];
    #pragma unroll
    for (int k = 0; k < RANK_VPT; ++k) {
        idx[k] = i0 + k * stride;
        if (idx[k] < total)
            di[k] = (idx[k] < E) ? dstE[idx[k]] : idx[k] - E;
    }
    #pragma unroll
    for (int k = 0; k < RANK_VPT; ++k)
        if (idx[k] < total) r[k] = atomicAdd(&cnt[di[k]], 1);
    #pragma unroll
    for (int k = 0; k < RANK_VPT; ++k)
        if (idx[k] < total) rank[idx[k]] = r[k];
}

// ---- CSR build pass C: atomic-free placement ----
__global__ __launch_bounds__(256) void place_k(
    const int* __restrict__ srcE, const int* __restrict__ dstE,
    const int* __restrict__ rowptr, const int* __restrict__ rank,
    int* __restrict__ ssrc, int E, int N) {
    long long i = (long long)blockIdx.x * 256 + threadIdx.x;
    if (i >= (long long)E + N) return;
    int si, di;
    if (i < E) { si = srcE[i]; di = dstE[i]; }
    else       { si = di = (int)(i - E); }
    ssrc[rowptr[di] + rank[i]] = si;
}

// ---- 3-phase multi-block exclusive scan ----
__global__ __launch_bounds__(256) void scan_part_k(
    const int* __restrict__ cnt, int* __restrict__ part, int N) {
    __shared__ int wsum[4];
    const int base = blockIdx.x * SCAN_SEG;
    const int lim = min(base + SCAN_SEG, N);
    int s = 0;
    for (int i = base + threadIdx.x; i < lim; i += 256) s += cnt[i];
    #pragma unroll
    for (int off = 32; off; off >>= 1) s += __shfl_down(s, off);
    if ((threadIdx.x & 63) == 0) wsum[threadIdx.x >> 6] = s;
    __syncthreads();
    if (threadIdx.x == 0) part[blockIdx.x] = wsum[0] + wsum[1] + wsum[2] + wsum[3];
}

__global__ void scan_offsets_k(int* __restrict__ part, int nseg,
                               int* __restrict__ rowptr, int N) {
    if (threadIdx.x == 0) {
        int run = 0;
        for (int i = 0; i < nseg; ++i) { int c = part[i]; part[i] = run; run += c; }
        rowptr[N] = run;
    }
}

__global__ __launch_bounds__(256) void scan_write_k(
    int* __restrict__ cnt, int* __restrict__ rowptr,
    const int* __restrict__ part, int N) {
    __shared__ int wsum[4];
    const int tid = threadIdx.x;
    const int lane = tid & 63;
    const int wv = tid >> 6;
    const int tbase = blockIdx.x * SCAN_SEG + tid * 8;
    int local[8];
    int s = 0;
    #pragma unroll
    for (int q = 0; q < 8; ++q) {
        int idx = tbase + q;
        int c = (idx < N) ? cnt[idx] : 0;
        local[q] = s;
        s += c;
    }
    int incl = s;
    #pragma unroll
    for (int off = 1; off < 64; off <<= 1) {
        int t = __shfl_up(incl, off);
        if (lane >= off) incl += t;
    }
    if (lane == 63) wsum[wv] = incl;
    __syncthreads();
    if (tid == 0) {
        int r = 0;
        #pragma unroll
        for (int i = 0; i < 4; ++i) { int c = wsum[i]; wsum[i] = r; r += c; }
    }
    __syncthreads();
    const int base = part[blockIdx.x] + wsum[wv] + (incl - s);
    #pragma unroll
    for (int q = 0; q < 8; ++q) {
        int idx = tbase + q;
        if (idx < N) rowptr[idx] = base + local[q];
    }
}

// ---- fused softmax + weighted gather. One wave/node, 4 groups x 16 lanes.
// No max pass (logits bounded; softmax shift-invariant).
// OUTBF: write bf16 (aggx). else: f32 + bias (final output).
template <bool OUTBF>
__global__ __launch_bounds__(256) void node_gather_k(
    const int* __restrict__ rowptr, const int* __restrict__ ssrc,
    const float* __restrict__ s, const float* __restrict__ d,
    const unsigned short* __restrict__ hsrc, const float* __restrict__ bias,
    unsigned short* __restrict__ obf, float* __restrict__ outf, int N) {
    constexpr int F = 128, G = 4;
    const int node = blockIdx.x * 4 + (threadIdx.x >> 6);
    const int lane = threadIdx.x & 63;
    if (node >= N) return;
    const int beg = rowptr[node];
    const int end = rowptr[node + 1];
    const float dn = d[node];
    const int grp = lane >> 4;   // 0..3
    const int lr = lane & 15;    // 0..15

    float acc[8] = {};
    float zsum = 0.f;
    for (int j = beg + grp; j < end; j += G) {
        int sj = ssrc[j];                       // broadcast within group
        float e = s[sj] + dn;                   // broadcast within group
        e = (e > 0.f) ? e : NEG_SLOPE * e;
        float exj = __expf(e);
        zsum += exj;
        bf16x8 v = *(const bf16x8*)(hsrc + (size_t)sj * F + lr * 8);
        #pragma unroll
        for (int q = 0; q < 8; ++q)
            acc[q] += exj * bf2f(((unsigned short*)&v)[q]);
    }
    // reduce across the 4 groups (lanes with equal lr)
    #pragma unroll
    for (int off = 16; off < 64; off <<= 1) {
        zsum += __shfl_xor(zsum, off);
        #pragma unroll
        for (int q = 0; q < 8; ++q) acc[q] += __shfl_xor(acc[q], off);
    }
    const float inv = 1.f / zsum;

    if (lane < 16) {
        if constexpr (OUTBF) {
            bf16x8 w;
            #pragma unroll
            for (int q = 0; q < 8; ++q)
                ((unsigned short*)&w)[q] = f2bf(acc[q] * inv);
            *(bf16x8*)(obf + (size_t)node * F + lr * 8) = w;
        } else {
            float o[8];
            #pragma unroll
            for (int q = 0; q < 8; ++q)
                o[q] = acc[q] * inv + bias[lr * 8 + q];
            float* op = outf + (size_t)node * F + lr * 8;
            *(float4*)op = {o[0], o[1], o[2], o[3]};
            *(float4*)(op + 4) = {o[4], o[5], o[6], o[7]};
        }
    }
}

extern "C" void kernel_launch(void* const* d_in, const int* in_sizes, int n_in,
                              void* d_out, int out_size, void* d_ws, size_t ws_size,
                              hipStream_t stream) {
    const float* x      = (const float*)d_in[0];
    const int*   eidx   = (const int*)d_in[1];
    const float* W1     = (const float*)d_in[2];
    const float* a_src1 = (const float*)d_in[3];
    const float* a_dst1 = (const float*)d_in[4];
    const float* b1     = (const float*)d_in[5];
    const float* W2     = (const float*)d_in[6];
    const float* a_src2 = (const float*)d_in[7];
    const float* a_dst2 = (const float*)d_in[8];
    const float* b2     = (const float*)d_in[9];

    const int N = in_sizes[0] / 128;   // 50000
    const int E = in_sizes[1] / 2;     // 800000
    const int F_IN = 128, H = 256, F_OUT = 128;
    const int EA = E + N;

    const int* srcE = eidx;
    const int* dstE = eidx + E;

    // ---- workspace layout (~73 MB) ----
    unsigned short* xbf    = (unsigned short*)d_ws;                 // N*128 bf16
    unsigned short* aggx   = xbf + (size_t)N * F_IN;                // N*128 bf16
    unsigned short* g1     = aggx + (size_t)N * F_IN;               // N*256 bf16
    unsigned short* h2bf   = g1 + (size_t)N * H;                    // N*128 bf16
    float*          sbuf   = (float*)(h2bf + (size_t)N * F_OUT);    // N
    float*          dbuf   = sbuf + N;                              // N
    float*          w_s1   = dbuf + N;                              // 128
    float*          w_d1   = w_s1 + F_IN;                           // 128
    unsigned short* w1T    = (unsigned short*)(w_d1 + F_IN);        // 256*128
    unsigned short* w2T    = w1T + 32768;                           // 128*256
    int*            rowptr = (int*)(w2T + 32768);                   // N+1
    int*            cnt    = rowptr + (N + 1);                      // N
    int*            part   = cnt + N;                               // 32
    int*            ssrc   = part + 32;                             // E+N
    int*            rank   = ssrc + EA;                             // E+N

    float* out = (float*)d_out;

    // ---------------- CSR build ----------------
    {
        hipMemsetAsync(cnt, 0, (size_t)N * 4, stream);
        int stride = (EA + RANK_VPT - 1) / RANK_VPT;
        int rblocks = (stride + 255) / 256;
        stride = rblocks * 256;
        rank_k<<<rblocks, 256, 0, stream>>>(dstE, cnt, rank, E, N, stride);
        int nseg = (N + SCAN_SEG - 1) / SCAN_SEG;
        scan_part_k<<<nseg, 256, 0, stream>>>(cnt, part, N);
        scan_offsets_k<<<1, 64, 0, stream>>>(part, nseg, rowptr, N);
        scan_write_k<<<nseg, 256, 0, stream>>>(cnt, rowptr, part, N);
        int eb = (EA + 255) / 256;
        place_k<<<eb, 256, 0, stream>>>(srcE, dstE, rowptr, rank, ssrc, E, N);
    }

    // ---------------- prep: projections, weight transposes, x->bf16 --------
    rowdot_k<256><<<32, 256, 0, stream>>>(W1, a_src1, a_dst1, w_s1, w_d1, F_IN);
    wt_bf_k<<<(F_IN * H + 255) / 256, 256, 0, stream>>>(W1, w1T, F_IN, H);
    wt_bf_k<<<(H * F_OUT + 255) / 256, 256, 0, stream>>>(W2, w2T, H, F_OUT);
    {
        long n4 = (long)N * F_IN / 4;
        xbf_k<<<(int)((n4 + 255) / 256), 256, 0, stream>>>(
            (const float4*)x, (ushort4*)xbf, n4);
    }

    // ---------------- layer 1: rowdot -> gather(x) -> GEMM ----------------
    {
        int rb = (N * 64 + 255) / 256;
        rowdot_bf_k<<<rb, 256, 0, stream>>>(xbf, w_s1, w_d1, sbuf, dbuf, N);

        int nb = (N + 3) / 4;
        node_gather_k<true><<<nb, 256, 0, stream>>>(
            rowptr, ssrc, sbuf, dbuf, xbf, nullptr, aggx, nullptr, N);

        dim3 gg((N + 127) / 128, H / 64);
        gemm_bf16<128, 256, 1><<<gg, 256, 0, stream>>>(aggx, w1T, g1, b1, N);
    }

    // ---------------- layer 2: GEMM -> rowdot -> gather(h2) ----------------
    {
        dim3 gg((N + 127) / 128, F_OUT / 64);
        gemm_bf16<256, 128, 2><<<gg, 256, 0, stream>>>(g1, w2T, h2bf, nullptr, N);

        int rb = (N * 64 + 255) / 256;
        rowdot_bf_k<<<rb, 256, 0, stream>>>(h2bf, a_src2, a_dst2, sbuf, dbuf, N);

        int nb = (N + 3) / 4;
        node_gather_k<false><<<nb, 256, 0, stream>>>(
            rowptr, ssrc, sbuf, dbuf, h2bf, b2, nullptr, out, N);
    }
}

// Round 10
// 202.571 us; speedup vs baseline: 22.8545x; 1.0631x over previous
//
#include <hip/hip_runtime.h>
#include <hip/hip_bf16.h>

// ---------------------------------------------------------------------------
// GAT encoder, 2 layers. Round 10: round-9 structure + latency-optimized
// gather (2-edge unrolled groups -> 2x memory-level parallelism), fused
// x->bf16+rowdot prep, deeper-batched rank atomics.
// ---------------------------------------------------------------------------

#define NEG_SLOPE 0.2f
#define SCAN_SEG 2048

typedef __attribute__((ext_vector_type(8))) short bf16x8;
typedef __attribute__((ext_vector_type(4))) float f32x4;

__device__ __forceinline__ unsigned short f2bf(float v) {
    __hip_bfloat16 b = __float2bfloat16(v);
    return *reinterpret_cast<unsigned short*>(&b);
}
__device__ __forceinline__ float bf2f(unsigned short u) {
    __hip_bfloat16 b = *reinterpret_cast<__hip_bfloat16*>(&u);
    return __bfloat162float(b);
}

// ---- fused: x f32 -> bf16 copy + s,d row dots. One wave per node. ----
__global__ __launch_bounds__(256) void xprep_k(
    const float* __restrict__ x, const float* __restrict__ va,
    const float* __restrict__ vb, unsigned short* __restrict__ xbf,
    float* __restrict__ s, float* __restrict__ d, int N) {
    int w = (blockIdx.x * 256 + threadIdx.x) >> 6;
    int lane = threadIdx.x & 63;
    if (w >= N) return;
    float2 v = *(const float2*)(x + (size_t)w * 128 + lane * 2);
    ushort2 u;
    u.x = f2bf(v.x);
    u.y = f2bf(v.y);
    *(ushort2*)(xbf + (size_t)w * 128 + lane * 2) = u;
    float ss = v.x * va[lane * 2] + v.y * va[lane * 2 + 1];
    float dd = v.x * vb[lane * 2] + v.y * vb[lane * 2 + 1];
    #pragma unroll
    for (int off = 32; off; off >>= 1) {
        ss += __shfl_down(ss, off);
        dd += __shfl_down(dd, off);
    }
    if (lane == 0) { s[w] = ss; d[w] = dd; }
}

// ---- weight transpose: W[K][Nn] f32 -> WT [Nn][K] bf16 ----
__global__ __launch_bounds__(256) void wt_bf_k(
    const float* __restrict__ W, unsigned short* __restrict__ T, int K, int Nn) {
    int i = blockIdx.x * 256 + threadIdx.x;
    if (i >= K * Nn) return;
    int k = i / Nn, n = i - k * Nn;
    T[(size_t)n * K + k] = f2bf(W[i]);
}

// ---- plain bf16 MFMA GEMM: A[M][K] bf16 @ BT[NN][K] bf16 -> [M][NN] ----
// EPI=1: relu(acc+bias[col]) -> bf16. EPI=2: plain bf16.
template <int K, int NN, int EPI>
__global__ __launch_bounds__(256) void gemm_bf16(
    const unsigned short* __restrict__ A, const unsigned short* __restrict__ BT,
    unsigned short* __restrict__ C, const float* __restrict__ bias, int M) {
    constexpr int BK = 32, PAD = 8;
    __shared__ short As[128][BK + PAD];
    __shared__ short Bs[64][BK + PAD];
    const int tid = threadIdx.x;
    const int wv = tid >> 6;
    const int ln = tid & 63;
    const int row0 = blockIdx.x * 128;
    const int col0 = blockIdx.y * 64;

    f32x4 acc[2][4];
    #pragma unroll
    for (int m = 0; m < 2; ++m)
        #pragma unroll
        for (int n = 0; n < 4; ++n) acc[m][n] = {0.f, 0.f, 0.f, 0.f};

    const int l15 = ln & 15;
    const int kg = (ln >> 4) * 8;

    for (int k0 = 0; k0 < K; k0 += BK) {
        #pragma unroll
        for (int t = 0; t < 2; ++t) {
            int v = tid + t * 256;
            int r = v >> 2;
            int kc = (v & 3) * 8;
            bf16x8 val = {0, 0, 0, 0, 0, 0, 0, 0};
            int gr = row0 + r;
            if (gr < M)
                val = *(const bf16x8*)(A + (size_t)gr * K + k0 + kc);
            *(bf16x8*)(&As[r][kc]) = val;
        }
        {
            int c = tid >> 2;
            int kc = (tid & 3) * 8;
            *(bf16x8*)(&Bs[c][kc]) =
                *(const bf16x8*)(BT + (size_t)(col0 + c) * K + k0 + kc);
        }
        __syncthreads();

        bf16x8 ah[2], bh[4];
        #pragma unroll
        for (int m = 0; m < 2; ++m)
            ah[m] = *(const bf16x8*)&As[wv * 32 + m * 16 + l15][kg];
        #pragma unroll
        for (int n = 0; n < 4; ++n)
            bh[n] = *(const bf16x8*)&Bs[n * 16 + l15][kg];
        #pragma unroll
        for (int m = 0; m < 2; ++m)
            #pragma unroll
            for (int n = 0; n < 4; ++n)
                acc[m][n] = __builtin_amdgcn_mfma_f32_16x16x32_bf16(
                    ah[m], bh[n], acc[m][n], 0, 0, 0);
        __syncthreads();
    }

    // C/D layout: col=lane&15, row=(lane>>4)*4+reg
    const int crow = (ln >> 4) * 4;
    #pragma unroll
    for (int m = 0; m < 2; ++m) {
        #pragma unroll
        for (int n = 0; n < 4; ++n) {
            int gr0 = row0 + wv * 32 + m * 16 + crow;
            int gc = col0 + n * 16 + l15;
            #pragma unroll
            for (int q = 0; q < 4; ++q) {
                int gr = gr0 + q;
                if (gr >= M) continue;
                if constexpr (EPI == 1) {
                    float v = acc[m][n][q] + bias[gc];
                    v = fmaxf(v, 0.f);
                    C[(size_t)gr * NN + gc] = f2bf(v);
                } else {
                    C[(size_t)gr * NN + gc] = f2bf(acc[m][n][q]);
                }
            }
        }
    }
}

// ---- per-node dots (f32 source): s[n]=h[n,:]·va, d[n]=h[n,:]·vb ----
template <int F>
__global__ __launch_bounds__(256) void rowdot_k(
    const float* __restrict__ h, const float* __restrict__ va,
    const float* __restrict__ vb, float* __restrict__ s,
    float* __restrict__ d, int N) {
    int w = (blockIdx.x * 256 + threadIdx.x) >> 6;
    int lane = threadIdx.x & 63;
    if (w >= N) return;
    const float* hp = h + (size_t)w * F;
    float ss = 0.f, dd = 0.f;
    #pragma unroll
    for (int f = lane; f < F; f += 64) {
        float v = hp[f];
        ss += v * va[f];
        dd += v * vb[f];
    }
    #pragma unroll
    for (int off = 32; off; off >>= 1) {
        ss += __shfl_down(ss, off);
        dd += __shfl_down(dd, off);
    }
    if (lane == 0) { s[w] = ss; d[w] = dd; }
}

// ---- per-node dots (bf16 source, F=128) ----
__global__ __launch_bounds__(256) void rowdot_bf_k(
    const unsigned short* __restrict__ h, const float* __restrict__ va,
    const float* __restrict__ vb, float* __restrict__ s,
    float* __restrict__ d, int N) {
    int w = (blockIdx.x * 256 + threadIdx.x) >> 6;
    int lane = threadIdx.x & 63;
    if (w >= N) return;
    ushort2 u = *(const ushort2*)(h + (size_t)w * 128 + lane * 2);
    float v0 = bf2f(u.x), v1 = bf2f(u.y);
    float ss = v0 * va[lane * 2] + v1 * va[lane * 2 + 1];
    float dd = v0 * vb[lane * 2] + v1 * vb[lane * 2 + 1];
    #pragma unroll
    for (int off = 32; off; off >>= 1) {
        ss += __shfl_down(ss, off);
        dd += __shfl_down(dd, off);
    }
    if (lane == 0) { s[w] = ss; d[w] = dd; }
}

// ---- CSR build pass A: rank = within-dst arrival order; cnt = histogram ----
#define RANK_VPT 16
__global__ __launch_bounds__(256) void rank_k(
    const int* __restrict__ dstE, int* __restrict__ cnt,
    int* __restrict__ rank, int E, int N, int stride) {
    const int i0 = blockIdx.x * 256 + threadIdx.x;
    const int total = E + N;
    int idx[RANK_VPT], di[RANK_VPT], r[RANK_VPT];
    #pragma unroll
    for (int k = 0; k < RANK_VPT; ++k) {
        idx[k] = i0 + k * stride;
        if (idx[k] < total)
            di[k] = (idx[k] < E) ? dstE[idx[k]] : idx[k] - E;
    }
    #pragma unroll
    for (int k = 0; k < RANK_VPT; ++k)
        if (idx[k] < total) r[k] = atomicAdd(&cnt[di[k]], 1);
    #pragma unroll
    for (int k = 0; k < RANK_VPT; ++k)
        if (idx[k] < total) rank[idx[k]] = r[k];
}

// ---- CSR build pass C: atomic-free placement ----
__global__ __launch_bounds__(256) void place_k(
    const int* __restrict__ srcE, const int* __restrict__ dstE,
    const int* __restrict__ rowptr, const int* __restrict__ rank,
    int* __restrict__ ssrc, int E, int N) {
    long long i = (long long)blockIdx.x * 256 + threadIdx.x;
    if (i >= (long long)E + N) return;
    int si, di;
    if (i < E) { si = srcE[i]; di = dstE[i]; }
    else       { si = di = (int)(i - E); }
    ssrc[rowptr[di] + rank[i]] = si;
}

// ---- 3-phase multi-block exclusive scan ----
__global__ __launch_bounds__(256) void scan_part_k(
    const int* __restrict__ cnt, int* __restrict__ part, int N) {
    __shared__ int wsum[4];
    const int base = blockIdx.x * SCAN_SEG;
    const int lim = min(base + SCAN_SEG, N);
    int s = 0;
    for (int i = base + threadIdx.x; i < lim; i += 256) s += cnt[i];
    #pragma unroll
    for (int off = 32; off; off >>= 1) s += __shfl_down(s, off);
    if ((threadIdx.x & 63) == 0) wsum[threadIdx.x >> 6] = s;
    __syncthreads();
    if (threadIdx.x == 0) part[blockIdx.x] = wsum[0] + wsum[1] + wsum[2] + wsum[3];
}

__global__ void scan_offsets_k(int* __restrict__ part, int nseg,
                               int* __restrict__ rowptr, int N) {
    if (threadIdx.x == 0) {
        int run = 0;
        for (int i = 0; i < nseg; ++i) { int c = part[i]; part[i] = run; run += c; }
        rowptr[N] = run;
    }
}

__global__ __launch_bounds__(256) void scan_write_k(
    int* __restrict__ cnt, int* __restrict__ rowptr,
    const int* __restrict__ part, int N) {
    __shared__ int wsum[4];
    const int tid = threadIdx.x;
    const int lane = tid & 63;
    const int wv = tid >> 6;
    const int tbase = blockIdx.x * SCAN_SEG + tid * 8;
    int local[8];
    int s = 0;
    #pragma unroll
    for (int q = 0; q < 8; ++q) {
        int idx = tbase + q;
        int c = (idx < N) ? cnt[idx] : 0;
        local[q] = s;
        s += c;
    }
    int incl = s;
    #pragma unroll
    for (int off = 1; off < 64; off <<= 1) {
        int t = __shfl_up(incl, off);
        if (lane >= off) incl += t;
    }
    if (lane == 63) wsum[wv] = incl;
    __syncthreads();
    if (tid == 0) {
        int r = 0;
        #pragma unroll
        for (int i = 0; i < 4; ++i) { int c = wsum[i]; wsum[i] = r; r += c; }
    }
    __syncthreads();
    const int base = part[blockIdx.x] + wsum[wv] + (incl - s);
    #pragma unroll
    for (int q = 0; q < 8; ++q) {
        int idx = tbase + q;
        if (idx < N) rowptr[idx] = base + local[q];
    }
}

// ---- fused softmax + weighted gather. One wave/node, 4 groups x 16 lanes,
// 2-edge unrolled (2x row loads in flight). No max pass.
// OUTBF: write bf16 (aggx). else: f32 + bias (final output).
template <bool OUTBF>
__global__ __launch_bounds__(256) void node_gather_k(
    const int* __restrict__ rowptr, const int* __restrict__ ssrc,
    const float* __restrict__ s, const float* __restrict__ d,
    const unsigned short* __restrict__ hsrc, const float* __restrict__ bias,
    unsigned short* __restrict__ obf, float* __restrict__ outf, int N) {
    constexpr int F = 128, G = 4;
    const int node = blockIdx.x * 4 + (threadIdx.x >> 6);
    const int lane = threadIdx.x & 63;
    if (node >= N) return;
    const int beg = rowptr[node];
    const int end = rowptr[node + 1];
    const float dn = d[node];
    const int grp = lane >> 4;   // 0..3
    const int lr = lane & 15;    // 0..15

    float acc[8] = {};
    float zsum = 0.f;
    int j = beg + grp;
    // pairs: both edges' loads issued before any accumulation
    for (; j + G < end; j += 2 * G) {
        int sj0 = ssrc[j];
        int sj1 = ssrc[j + G];
        float e0 = s[sj0] + dn;
        float e1 = s[sj1] + dn;
        bf16x8 v0 = *(const bf16x8*)(hsrc + (size_t)sj0 * F + lr * 8);
        bf16x8 v1 = *(const bf16x8*)(hsrc + (size_t)sj1 * F + lr * 8);
        e0 = (e0 > 0.f) ? e0 : NEG_SLOPE * e0;
        e1 = (e1 > 0.f) ? e1 : NEG_SLOPE * e1;
        float x0 = __expf(e0);
        float x1 = __expf(e1);
        zsum += x0 + x1;
        #pragma unroll
        for (int q = 0; q < 8; ++q) {
            acc[q] += x0 * bf2f(((unsigned short*)&v0)[q]);
            acc[q] += x1 * bf2f(((unsigned short*)&v1)[q]);
        }
    }
    if (j < end) {
        int sj = ssrc[j];
        float e = s[sj] + dn;
        e = (e > 0.f) ? e : NEG_SLOPE * e;
        float exj = __expf(e);
        zsum += exj;
        bf16x8 v = *(const bf16x8*)(hsrc + (size_t)sj * F + lr * 8);
        #pragma unroll
        for (int q = 0; q < 8; ++q)
            acc[q] += exj * bf2f(((unsigned short*)&v)[q]);
    }
    // reduce across the 4 groups (lanes with equal lr)
    #pragma unroll
    for (int off = 16; off < 64; off <<= 1) {
        zsum += __shfl_xor(zsum, off);
        #pragma unroll
        for (int q = 0; q < 8; ++q) acc[q] += __shfl_xor(acc[q], off);
    }
    const float inv = 1.f / zsum;

    if (lane < 16) {
        if constexpr (OUTBF) {
            bf16x8 w;
            #pragma unroll
            for (int q = 0; q < 8; ++q)
                ((unsigned short*)&w)[q] = f2bf(acc[q] * inv);
            *(bf16x8*)(obf + (size_t)node * F + lr * 8) = w;
        } else {
            float o[8];
            #pragma unroll
            for (int q = 0; q < 8; ++q)
                o[q] = acc[q] * inv + bias[lr * 8 + q];
            float* op = outf + (size_t)node * F + lr * 8;
            *(float4*)op = {o[0], o[1], o[2], o[3]};
            *(float4*)(op + 4) = {o[4], o[5], o[6], o[7]};
        }
    }
}

extern "C" void kernel_launch(void* const* d_in, const int* in_sizes, int n_in,
                              void* d_out, int out_size, void* d_ws, size_t ws_size,
                              hipStream_t stream) {
    const float* x      = (const float*)d_in[0];
    const int*   eidx   = (const int*)d_in[1];
    const float* W1     = (const float*)d_in[2];
    const float* a_src1 = (const float*)d_in[3];
    const float* a_dst1 = (const float*)d_in[4];
    const float* b1     = (const float*)d_in[5];
    const float* W2     = (const float*)d_in[6];
    const float* a_src2 = (const float*)d_in[7];
    const float* a_dst2 = (const float*)d_in[8];
    const float* b2     = (const float*)d_in[9];

    const int N = in_sizes[0] / 128;   // 50000
    const int E = in_sizes[1] / 2;     // 800000
    const int F_IN = 128, H = 256, F_OUT = 128;
    const int EA = E + N;

    const int* srcE = eidx;
    const int* dstE = eidx + E;

    // ---- workspace layout (~73 MB) ----
    unsigned short* xbf    = (unsigned short*)d_ws;                 // N*128 bf16
    unsigned short* aggx   = xbf + (size_t)N * F_IN;                // N*128 bf16
    unsigned short* g1     = aggx + (size_t)N * F_IN;               // N*256 bf16
    unsigned short* h2bf   = g1 + (size_t)N * H;                    // N*128 bf16
    float*          sbuf   = (float*)(h2bf + (size_t)N * F_OUT);    // N
    float*          dbuf   = sbuf + N;                              // N
    float*          w_s1   = dbuf + N;                              // 128
    float*          w_d1   = w_s1 + F_IN;                           // 128
    unsigned short* w1T    = (unsigned short*)(w_d1 + F_IN);        // 256*128
    unsigned short* w2T    = w1T + 32768;                           // 128*256
    int*            rowptr = (int*)(w2T + 32768);                   // N+1
    int*            cnt    = rowptr + (N + 1);                      // N
    int*            part   = cnt + N;                               // 32
    int*            ssrc   = part + 32;                             // E+N
    int*            rank   = ssrc + EA;                             // E+N

    float* out = (float*)d_out;

    // ---------------- CSR build ----------------
    {
        hipMemsetAsync(cnt, 0, (size_t)N * 4, stream);
        int stride = (EA + RANK_VPT - 1) / RANK_VPT;
        int rblocks = (stride + 255) / 256;
        stride = rblocks * 256;
        rank_k<<<rblocks, 256, 0, stream>>>(dstE, cnt, rank, E, N, stride);
        int nseg = (N + SCAN_SEG - 1) / SCAN_SEG;
        scan_part_k<<<nseg, 256, 0, stream>>>(cnt, part, N);
        scan_offsets_k<<<1, 64, 0, stream>>>(part, nseg, rowptr, N);
        scan_write_k<<<nseg, 256, 0, stream>>>(cnt, rowptr, part, N);
        int eb = (EA + 255) / 256;
        place_k<<<eb, 256, 0, stream>>>(srcE, dstE, rowptr, rank, ssrc, E, N);
    }

    // ---------------- prep: projections + weight transposes ----------------
    rowdot_k<256><<<32, 256, 0, stream>>>(W1, a_src1, a_dst1, w_s1, w_d1, F_IN);
    wt_bf_k<<<(F_IN * H + 255) / 256, 256, 0, stream>>>(W1, w1T, F_IN, H);
    wt_bf_k<<<(H * F_OUT + 255) / 256, 256, 0, stream>>>(W2, w2T, H, F_OUT);

    // ---------------- layer 1: xprep -> gather(x) -> GEMM ----------------
    {
        int rb = (N * 64 + 255) / 256;
        xprep_k<<<rb, 256, 0, stream>>>(x, w_s1, w_d1, xbf, sbuf, dbuf, N);

        int nb = (N + 3) / 4;
        node_gather_k<true><<<nb, 256, 0, stream>>>(
            rowptr, ssrc, sbuf, dbuf, xbf, nullptr, aggx, nullptr, N);

        dim3 gg((N + 127) / 128, H / 64);
        gemm_bf16<128, 256, 1><<<gg, 256, 0, stream>>>(aggx, w1T, g1, b1, N);
    }

    // ---------------- layer 2: GEMM -> rowdot -> gather(h2) ----------------
    {
        dim3 gg((N + 127) / 128, F_OUT / 64);
        gemm_bf16<256, 128, 2><<<gg, 256, 0, stream>>>(g1, w2T, h2bf, nullptr, N);

        int rb = (N * 64 + 255) / 256;
        rowdot_bf_k<<<rb, 256, 0, stream>>>(h2bf, a_src2, a_dst2, sbuf, dbuf, N);

        int nb = (N + 3) / 4;
        node_gather_k<false><<<nb, 256, 0, stream>>>(
            rowptr, ssrc, sbuf, dbuf, h2bf, b2, nullptr, out, N);
    }
}